// Round 11
// baseline (330.654 us; speedup 1.0000x reference)
//
#include <hip/hip_runtime.h>

typedef unsigned short u16;
typedef __attribute__((ext_vector_type(4))) float floatx4;
typedef __attribute__((ext_vector_type(8))) __bf16 bf16x8;
typedef __attribute__((ext_vector_type(4))) unsigned short ushort4v;
typedef __attribute__((ext_vector_type(8))) unsigned short ushort8v;

#define DI __device__ __forceinline__

// ---- problem constants ----
// B=8, C=512, T=1024, H=8, F=2048, KS=3, head dim 64, ROPE_D=32, EPS=1e-4

DI u16 f2bf(float f) {
  union { float f; unsigned u; } v; v.f = f;
  unsigned r = v.u + 0x7fffu + ((v.u >> 16) & 1u);
  return (u16)(r >> 16);
}
DI float bf2f(u16 h) {
  union { unsigned u; float f; } v; v.u = ((unsigned)h) << 16;
  return v.f;
}

#define GLDS(g, l) __builtin_amdgcn_global_load_lds( \
    (const __attribute__((address_space(1))) unsigned int*)(g), \
    (__attribute__((address_space(3))) unsigned int*)(l), 16, 0, 0)

// ---------------------------------------------------------------------------
// Flash attention (R9 structure, unchanged).
// ---------------------------------------------------------------------------
__global__ __launch_bounds__(256, 2) void k_fattn(
    const u16* __restrict__ qb, const u16* __restrict__ kb,
    const u16* __restrict__ vb, const unsigned* __restrict__ mb,
    u16* __restrict__ oT)
{
  __shared__ __align__(16) u16 Ps[4][32 * 64];
  const int tid  = threadIdx.x;
  const int wave = tid >> 6, lane = tid & 63;
  const int lr = lane & 15, kg = lane >> 4;
  const int qt = blockIdx.x, bh = blockIdx.y;
  const int bb = bh >> 3, hh = bh & 7;
  const int wq0 = qt * 128 + wave * 32;
  const float L2E = 1.44269504f;

  const u16* Qp = qb + (size_t)bh * 65536;
  const u16* Kp = kb + (size_t)bh * 65536;
  const u16* Vp = vb + (size_t)bh * 65536;
  u16* Pw = &Ps[wave][0];

  bf16x8 qf[2][2];
#pragma unroll
  for (int i = 0; i < 2; ++i)
#pragma unroll
    for (int h = 0; h < 2; ++h)
      qf[i][h] = *(const bf16x8*)&Qp[(wq0 + i * 16 + lr) * 64 + h * 32 + kg * 8];

  float l_b[2] = {0.f, 0.f};
  floatx4 o_acc[2][4];
#pragma unroll
  for (int i = 0; i < 2; ++i)
#pragma unroll
    for (int j = 0; j < 4; ++j) o_acc[i][j] = (floatx4){0.f, 0.f, 0.f, 0.f};

  bf16x8 kf[4][2], vf[4][2];
#pragma unroll
  for (int a = 0; a < 4; ++a)
#pragma unroll
    for (int h = 0; h < 2; ++h)
      kf[a][h] = *(const bf16x8*)&Kp[(a * 16 + lr) * 64 + h * 32 + kg * 8];

  for (int it = 0; it < 16; ++it) {
    const int s0 = it * 64;
    unsigned mw[2][2];
#pragma unroll
    for (int b = 0; b < 2; ++b) {
      const size_t rw = ((size_t)bb << 15) + ((size_t)(wq0 + b * 16 + lr) << 5) + (s0 >> 5);
      mw[b][0] = mb[rw]; mw[b][1] = mb[rw + 1];
    }
    floatx4 sT[4][2];
    __builtin_amdgcn_s_setprio(1);
#pragma unroll
    for (int a = 0; a < 4; ++a) {
      sT[a][0] = (floatx4){0.f, 0.f, 0.f, 0.f};
      sT[a][1] = (floatx4){0.f, 0.f, 0.f, 0.f};
#pragma unroll
      for (int b = 0; b < 2; ++b)
#pragma unroll
        for (int h = 0; h < 2; ++h)
          sT[a][b] = __builtin_amdgcn_mfma_f32_16x16x32_bf16(kf[a][h], qf[b][h], sT[a][b], 0, 0, 0);
    }
    __builtin_amdgcn_s_setprio(0);
#pragma unroll
    for (int a = 0; a < 4; ++a)
#pragma unroll
      for (int h = 0; h < 2; ++h)
        vf[a][h] = *(const bf16x8*)&Vp[(a * 16 + lr) * 1024 + s0 + h * 32 + kg * 8];
    if (it < 15) {
      const int sn = s0 + 64;
#pragma unroll
      for (int a = 0; a < 4; ++a)
#pragma unroll
        for (int h = 0; h < 2; ++h)
          kf[a][h] = *(const bf16x8*)&Kp[(sn + a * 16 + lr) * 64 + h * 32 + kg * 8];
    }
#pragma unroll
    for (int b = 0; b < 2; ++b) {
      float sum = 0.f;
#pragma unroll
      for (int a = 0; a < 4; ++a)
#pragma unroll
        for (int r = 0; r < 4; ++r) {
          const int sl = a * 16 + kg * 4 + r;
          float sv = sT[a][b][r] * 0.125f;
          const unsigned wsel = (sl & 32) ? mw[b][1] : mw[b][0];
          if (!((wsel >> (sl & 31)) & 1u)) sv = -10000.f;
          const float p = exp2f(sv * L2E);
          sT[a][b][r] = p;
          sum += p;
        }
      sum += __shfl_xor(sum, 16);
      sum += __shfl_xor(sum, 32);
      l_b[b] += sum;
#pragma unroll
      for (int a = 0; a < 4; ++a) {
        ushort4v pk;
#pragma unroll
        for (int r = 0; r < 4; ++r) {
          __bf16 hv = (__bf16)sT[a][b][r];
          pk[r] = *(u16*)&hv;
        }
        const int sl0 = a * 16 + kg * 4;
        *(ushort4v*)&Pw[(b * 16 + lr) * 64 + (sl0 ^ ((lr & 7) << 3))] = pk;
      }
    }
    asm volatile("s_waitcnt lgkmcnt(0)" ::: "memory");
    __builtin_amdgcn_sched_barrier(0);
    bf16x8 pa[2][2];
#pragma unroll
    for (int i = 0; i < 2; ++i)
#pragma unroll
      for (int h = 0; h < 2; ++h)
        pa[i][h] = *(const bf16x8*)&Pw[(i * 16 + lr) * 64 + (((h * 4 + kg) ^ (lr & 7)) << 3)];
    __builtin_amdgcn_s_setprio(1);
#pragma unroll
    for (int jd = 0; jd < 4; ++jd)
#pragma unroll
      for (int i = 0; i < 2; ++i)
#pragma unroll
        for (int h = 0; h < 2; ++h)
          o_acc[i][jd] = __builtin_amdgcn_mfma_f32_16x16x32_bf16(pa[i][h], vf[jd][h], o_acc[i][jd], 0, 0, 0);
    __builtin_amdgcn_s_setprio(0);
  }
  float linv[2][4];
#pragma unroll
  for (int i = 0; i < 2; ++i)
#pragma unroll
    for (int r = 0; r < 4; ++r) linv[i][r] = 1.f / __shfl(l_b[i], kg * 4 + r);
#pragma unroll
  for (int i = 0; i < 2; ++i)
#pragma unroll
    for (int jd = 0; jd < 4; ++jd)
#pragma unroll
      for (int r = 0; r < 4; ++r) {
        const int t = wq0 + i * 16 + kg * 4 + r;
        const int c = hh * 64 + jd * 16 + lr;
        oT[((size_t)bb * 1024 + t) * 512 + c] = f2bf(o_acc[i][jd][r] * linv[i][r]);
      }
}

// ---------------------------------------------------------------------------
// Flat GEMM, gemm_bt form, XCD-swizzled. R11: BK=32 double-buffered LDS with
// COUNTED vmcnt (T4) + raw s_barrier — next tile's loads stay in flight
// across the barrier; never drain vmcnt to 0 in the main loop. Both-sides
// chunk swizzle retained (bank conflicts = 0). setprio around MFMA cluster.
// Hazards: (a) each wave runs vmcnt(N) before barrier -> all tile-t slices
// landed; (b) buffer overwritten only 2 barriers after last read; (c)
// sched_barrier(0) after inline-asm waits (rule 18).
// MODE 0=QKV(+bias+rope+scatter) 3=oproj(+bias -> y1T (B,T,C))
// MODE 4=conv1(relu*mask -> padded h1)
// MODE 5=conv2 split-K partial z -> o0 + z*(B*T*C), bias on z==0, *mask
// ---------------------------------------------------------------------------
template<int MODE, int BN, int TAPK>
__global__ __launch_bounds__(256) void k_cgemm(
    const u16* __restrict__ A, int lda,
    const u16* __restrict__ Bsrc, int ldb,
    int K,
    u16* __restrict__ o0, u16* __restrict__ o1, u16* __restrict__ o2,
    const float* __restrict__ bias,
    const float* __restrict__ ctab, const float* __restrict__ stab,
    const float* __restrict__ msk)
{
  constexpr int BM = 128;
  constexpr int FN = BN / 32;
  constexpr int ACH = 2;               // A loads/thread/tile (BM*32/8/256)
  constexpr int BCH = BN * 32 / (8 * 256);  // B loads/thread/tile (2 or 1)
  __shared__ __align__(16) u16 As[2][BM * 32];
  __shared__ __align__(16) u16 Bs[2][BN * 32];

  const int tid  = threadIdx.x;
  const int wave = tid >> 6, lane = tid & 63;
  const int wm = wave >> 1, wn = wave & 1;
  const int lr = lane & 15, kg = lane >> 4;

  // XCD-aware bijective swizzle (nwg % 8 == 0 for all our grids)
  const int nwg = gridDim.x * gridDim.y;
  const int h0  = blockIdx.y * gridDim.x + blockIdx.x;
  const int cpx = nwg >> 3;
  const int tl  = (h0 & 7) * cpx + (h0 >> 3);
  const int bx  = tl % gridDim.x;
  const int by  = tl / gridDim.x;

  const int m0 = bx * BM, n0 = by * BN;
  const int koff = blockIdx.z * K;

  auto stage = [&](int buf, int kglob) {
#pragma unroll
    for (int ch = 0; ch < ACH; ++ch) {
      const int idx = ch * 256 + tid;
      const int row = idx >> 2;
      const int kk = (((idx & 3) ^ ((row >> 1) & 3)) << 3);   // source pre-swizzle
      GLDS(A + (size_t)(m0 + row) * lda + (kglob + kk), &As[buf][idx * 8]);
    }
#pragma unroll
    for (int ch = 0; ch < BCH; ++ch) {
      const int idx = ch * 256 + tid;
      const int row = idx >> 2;
      const int kk = (((idx & 3) ^ ((row >> 1) & 3)) << 3);
      const int bt = n0 + row;
      const u16* src;
      if constexpr (TAPK == 0) {
        src = Bsrc + (size_t)bt * ldb + (kglob + kk);
      } else {
        const int tap = kglob / TAPK, off2 = kglob - tap * TAPK;
        const int b = bt >> 10, t = bt & 1023;
        src = Bsrc + ((size_t)(b * 1026 + t + tap)) * TAPK + off2 + kk;
      }
      GLDS(src, &Bs[buf][idx * 8]);
    }
  };

  floatx4 acc[4][FN];
#pragma unroll
  for (int i = 0; i < 4; ++i)
#pragma unroll
    for (int j = 0; j < FN; ++j) acc[i][j] = (floatx4){0.f, 0.f, 0.f, 0.f};

  const int csw = (kg ^ ((lr >> 1) & 3)) * 8;   // read-side chunk swizzle

  stage(0, koff);
  int cur = 0;
  for (int k0 = 0; k0 < K; k0 += 32) {
    const bool nx = (k0 + 32 < K);
    if (nx) stage(cur ^ 1, koff + k0 + 32);
    // wait only for CURRENT tile's loads (older); next tile's stay in flight
    if (nx) {
      if constexpr (ACH + BCH == 4) asm volatile("s_waitcnt vmcnt(4)" ::: "memory");
      else                          asm volatile("s_waitcnt vmcnt(3)" ::: "memory");
    } else {
      asm volatile("s_waitcnt vmcnt(0)" ::: "memory");
    }
    __builtin_amdgcn_sched_barrier(0);
    __builtin_amdgcn_s_barrier();      // all waves' tile-t slices landed
    bf16x8 af[4], bfr[FN];
#pragma unroll
    for (int i = 0; i < 4; ++i)
      af[i] = *(const bf16x8*)&As[cur][(wm * 64 + i * 16 + lr) * 32 + csw];
#pragma unroll
    for (int j = 0; j < FN; ++j)
      bfr[j] = *(const bf16x8*)&Bs[cur][(wn * (BN / 2) + j * 16 + lr) * 32 + csw];
    __builtin_amdgcn_s_setprio(1);
#pragma unroll
    for (int i = 0; i < 4; ++i)
#pragma unroll
      for (int j = 0; j < FN; ++j)
        acc[i][j] = __builtin_amdgcn_mfma_f32_16x16x32_bf16(af[i], bfr[j], acc[i][j], 0, 0, 0);
    __builtin_amdgcn_s_setprio(0);
    __builtin_amdgcn_s_barrier();      // protect buffer before overwrite
    cur ^= 1;
  }

  const int wrow0 = m0 + wm * 64;
  const int col0  = n0 + wn * (BN / 2);

  if constexpr (MODE == 0) {  // ---- QKV: bias + RoPE + scatter ----
    float v[4][FN][4];
#pragma unroll
    for (int i = 0; i < 4; ++i)
#pragma unroll
      for (int j = 0; j < FN; ++j)
#pragma unroll
        for (int r = 0; r < 4; ++r)
          v[i][j][r] = acc[i][j][r] + bias[wrow0 + i * 16 + kg * 4 + r];
    const int sec = wrow0 >> 9;            // 0=q 1=k 2=v
    const int hh  = (wrow0 & 511) >> 6;    // head
    if (sec < 2) {
#pragma unroll
      for (int j = 0; j < FN; ++j) {
        const int t = (col0 + j * 16 + lr) & 1023;
#pragma unroll
        for (int r = 0; r < 4; ++r) {
          const int a = kg * 4 + r;
          const float cv = ctab[t * 16 + a], sv = stab[t * 16 + a];
          const float a0 = v[0][j][r], a1 = v[1][j][r];
          v[0][j][r] = a0 * cv - a1 * sv;
          v[1][j][r] = a1 * cv + a0 * sv;
        }
      }
      u16* dst = (sec == 0) ? o0 : o1;     // q,k: (B,H,T,64)
#pragma unroll
      for (int i = 0; i < 4; ++i)
#pragma unroll
        for (int j = 0; j < FN; ++j) {
          const int bt = col0 + j * 16 + lr;
          const int b = bt >> 10, t = bt & 1023;
          ushort4v pk;
#pragma unroll
          for (int r = 0; r < 4; ++r) pk[r] = f2bf(v[i][j][r]);
          *(ushort4v*)&dst[(((size_t)b * 8 + hh) * 1024 + t) * 64 + i * 16 + kg * 4] = pk;
        }
    } else {                               // v: (B,H,64,T)
#pragma unroll
      for (int i = 0; i < 4; ++i)
#pragma unroll
        for (int j = 0; j < FN; ++j) {
          const int bt = col0 + j * 16 + lr;
          const int b = bt >> 10, t = bt & 1023;
#pragma unroll
          for (int r = 0; r < 4; ++r) {
            const int dk = i * 16 + kg * 4 + r;
            o2[(((size_t)b * 8 + hh) * 64 + dk) * 1024 + t] = f2bf(v[i][j][r]);
          }
        }
    }
  } else if constexpr (MODE == 3) {  // ---- O-proj: +bias -> y1T (B,T,C) ----
#pragma unroll
    for (int i = 0; i < 4; ++i)
#pragma unroll
      for (int j = 0; j < FN; ++j) {
        const int bt = col0 + j * 16 + lr;
        const int c0 = wrow0 + i * 16 + kg * 4;
        ushort4v pk;
#pragma unroll
        for (int r = 0; r < 4; ++r) pk[r] = f2bf(acc[i][j][r] + bias[c0 + r]);
        *(ushort4v*)&o0[(size_t)bt * 512 + c0] = pk;
      }
  } else if constexpr (MODE == 4) {  // ---- conv1: relu(acc+b1)*mask -> h1pad ----
#pragma unroll
    for (int i = 0; i < 4; ++i) {
      const int r0 = wrow0 + i * 16 + kg * 4;
#pragma unroll
      for (int j = 0; j < FN; ++j) {
        const int bt = col0 + j * 16 + lr;
        const int b = bt >> 10, t = bt & 1023;
        const float mv = msk[(size_t)b * 1024 + t];
        ushort4v pk;
#pragma unroll
        for (int r = 0; r < 4; ++r)
          pk[r] = f2bf(fmaxf(acc[i][j][r] + bias[r0 + r], 0.f) * mv);
        *(ushort4v*)&o0[((size_t)(b * 1026 + t + 1)) * 2048 + r0] = pk;
      }
    }
  } else {                           // ---- conv2 split-K partial z -> o0 + z*S ----
    u16* dst = o0 + (size_t)blockIdx.z * 8 * 1024 * 512;
    const bool z0 = (blockIdx.z == 0);
#pragma unroll
    for (int i = 0; i < 4; ++i)
#pragma unroll
      for (int j = 0; j < FN; ++j) {
        const int bt = col0 + j * 16 + lr;
        const int b = bt >> 10, t = bt & 1023;
        const int c0 = wrow0 + i * 16 + kg * 4;
        const float mv = msk[(size_t)b * 1024 + t];
        ushort4v pk;
#pragma unroll
        for (int r = 0; r < 4; ++r) {
          const float bv = z0 ? bias[c0 + r] : 0.f;
          pk[r] = f2bf((acc[i][j][r] + bv) * mv);
        }
        *(ushort4v*)&dst[(size_t)bt * 512 + c0] = pk;
      }
  }
}

// ---------------------------------------------------------------------------
// Fused prep mega-kernel (unchanged from R10).
// ---------------------------------------------------------------------------
__global__ __launch_bounds__(256) void k_prep(
    const float* __restrict__ wq, const float* __restrict__ wk,
    const float* __restrict__ wv, const float* __restrict__ wo,
    const float* __restrict__ w1, const float* __restrict__ w2,
    const float* __restrict__ bq, const float* __restrict__ bk,
    const float* __restrict__ bv, const float* __restrict__ am,
    u16* __restrict__ wqkv, u16* __restrict__ wob,
    u16* __restrict__ w1p, u16* __restrict__ w2p,
    float* __restrict__ bqkv, float* __restrict__ ctab, float* __restrict__ stab,
    unsigned* __restrict__ mbits, u16* __restrict__ x2p, u16* __restrict__ h1p)
{
  const int bid = blockIdx.x;
  if (bid < 4096) {
    const int seg = bid >> 10;
    const int i = (bid & 1023) * 256 + threadIdx.x;
    const float* src = (seg == 0) ? wq : (seg == 1) ? wk : (seg == 2) ? wv : wo;
    u16* dst = (seg < 3) ? (wqkv + (size_t)seg * 512 * 512) : wob;
    dst[i] = f2bf(src[i]);
  } else if (bid < 16384) {
    const int i = (bid - 4096) * 256 + threadIdx.x;
    const int f = i / 1536, rem = i % 1536;
    const int kk = rem >> 9, c = rem & 511;
    w1p[i] = f2bf(w1[f * 1536 + c * 3 + kk]);
  } else if (bid < 28672) {
    const int i = (bid - 16384) * 256 + threadIdx.x;
    const int c = i / 6144, rem = i % 6144;
    const int kk = rem >> 11, f = rem & 2047;
    w2p[i] = f2bf(w2[c * 6144 + f * 3 + kk]);
  } else if (bid < 29696) {
    const int i = (bid - 28672) * 256 + threadIdx.x;
    const float* src = am + (size_t)i * 32;
    unsigned w = 0;
#pragma unroll
    for (int q = 0; q < 32; ++q) w |= (src[q] != 0.f) ? (1u << q) : 0u;
    mbits[i] = w;
  } else if (bid < 29760) {
    const int i = (bid - 29696) * 256 + threadIdx.x;
    const int t = i >> 4, a = i & 15;
    const float theta = powf(10000.f, -(float)a / 16.f);
    const float ang = (float)t * theta;
    ctab[i] = cosf(ang);
    stab[i] = sinf(ang);
  } else if (bid == 29760) {
    for (int i = threadIdx.x; i < 1536; i += 256)
      bqkv[i] = (i < 512) ? bq[i] : (i < 1024) ? bk[i - 512] : bv[i - 1024];
  } else {
    int zb = bid - 29761;
    if (zb < 16) {
      const int b = zb >> 1;
      const size_t row = (zb & 1) ? 1025 : 0;
      u16* r = x2p + ((size_t)b * 1026 + row) * 512;
      for (int i = threadIdx.x; i < 512; i += 256) r[i] = 0;
    } else {
      zb -= 16;
      const int b = zb >> 1;
      const size_t row = (zb & 1) ? 1025 : 0;
      u16* r = h1p + ((size_t)b * 1026 + row) * 2048;
      for (int i = threadIdx.x; i < 2048; i += 256) r[i] = 0;
    }
  }
}

// tiled fp32 (B,R,TT) -> bf16 (B,TT,R) transpose-convert, column mask applied
__global__ __launch_bounds__(256) void k_tcvt(const float* __restrict__ in, u16* __restrict__ out,
                                              const float* __restrict__ msk, int R, int TT) {
  __shared__ u16 tile[64][65];
  const int b = blockIdx.z;
  const int r0 = blockIdx.x * 64, t0 = blockIdx.y * 64;
  const int tx = threadIdx.x & 63, ty = threadIdx.x >> 6;
  const float mv = msk ? msk[(size_t)b * TT + t0 + tx] : 1.f;
  const float* ib = in + (size_t)b * R * TT;
#pragma unroll
  for (int rr = ty; rr < 64; rr += 4)
    tile[rr][tx] = f2bf(ib[(size_t)(r0 + rr) * TT + t0 + tx] * mv);
  __syncthreads();
  u16* ob = out + (size_t)b * TT * R;
#pragma unroll
  for (int tt = ty; tt < 64; tt += 4)
    ob[(size_t)(t0 + tt) * R + r0 + tx] = tile[tx][tt];
}

// LN1: one wave per (b,t) row of 512. r = xbT + y1T (both (B,T,C) bf16).
__global__ __launch_bounds__(256) void k_ln1(
    const u16* __restrict__ xbT, const u16* __restrict__ y1T,
    const float* __restrict__ xm, const float* __restrict__ g,
    const float* __restrict__ be, u16* __restrict__ x2T, u16* __restrict__ x2p)
{
  const int lane = threadIdx.x & 63, wv = threadIdx.x >> 6;
  const int row = blockIdx.x * 4 + wv;          // b*1024 + t
  const int b = row >> 10, t = row & 1023;
  const size_t base = (size_t)row * 512 + lane * 8;
  ushort8v ux = *(const ushort8v*)&xbT[base];
  ushort8v uy = *(const ushort8v*)&y1T[base];
  float v[8];
  float sum = 0.f, ss = 0.f;
#pragma unroll
  for (int q = 0; q < 8; ++q) {
    v[q] = bf2f(ux[q]) + bf2f(uy[q]);
    sum += v[q]; ss += v[q] * v[q];
  }
#pragma unroll
  for (int o = 32; o; o >>= 1) { sum += __shfl_xor(sum, o); ss += __shfl_xor(ss, o); }
  const float mean = sum * (1.f / 512.f);
  const float var  = ss * (1.f / 512.f) - mean * mean;
  const float rs   = rsqrtf(var + 1e-4f);
  const float m    = xm[(size_t)b * 1024 + t];
  ushort8v on, om;
#pragma unroll
  for (int q = 0; q < 8; ++q) {
    const int c = lane * 8 + q;
    const float nv = (v[q] - mean) * rs * g[c] + be[c];
    on[q] = f2bf(nv);
    om[q] = f2bf(nv * m);
  }
  *(ushort8v*)&x2T[base] = on;
  *(ushort8v*)&x2p[((size_t)(b * 1026 + t + 1)) * 512 + lane * 8] = om;
}

// LN2 stats: one wave per row; r = x2T + sum of 4 conv2 partials
__global__ __launch_bounds__(256) void k_ln2_stats(
    const u16* __restrict__ x2T, const u16* __restrict__ c2p,
    float2* __restrict__ mr)
{
  constexpr size_t S = (size_t)8 * 1024 * 512;
  const int lane = threadIdx.x & 63, wv = threadIdx.x >> 6;
  const int row = blockIdx.x * 4 + wv;
  const size_t base = (size_t)row * 512 + lane * 8;
  ushort8v u0 = *(const ushort8v*)&x2T[base];
  ushort8v u1 = *(const ushort8v*)&c2p[base];
  ushort8v u2 = *(const ushort8v*)&c2p[S + base];
  ushort8v u3 = *(const ushort8v*)&c2p[2 * S + base];
  ushort8v u4 = *(const ushort8v*)&c2p[3 * S + base];
  float sum = 0.f, ss = 0.f;
#pragma unroll
  for (int q = 0; q < 8; ++q) {
    const float v = bf2f(u0[q]) + bf2f(u1[q]) + bf2f(u2[q]) + bf2f(u3[q]) + bf2f(u4[q]);
    sum += v; ss += v * v;
  }
#pragma unroll
  for (int o = 32; o; o >>= 1) { sum += __shfl_xor(sum, o); ss += __shfl_xor(ss, o); }
  if (lane == 0) {
    const float mean = sum * (1.f / 512.f);
    const float var  = ss * (1.f / 512.f) - mean * mean;
    mr[row] = (float2){mean, rsqrtf(var + 1e-4f)};
  }
}

// LN2 write: normalize + transpose to out (B,C,T) fp32.
__global__ __launch_bounds__(256) void k_ln2_write(
    const u16* __restrict__ x2T, const u16* __restrict__ c2p,
    const float2* __restrict__ mr,
    const float* __restrict__ g, const float* __restrict__ be,
    float* __restrict__ out)
{
  constexpr size_t S = (size_t)8 * 1024 * 512;
  __shared__ float tile[64][65];
  const int cc0 = blockIdx.x * 64, t0 = blockIdx.y * 64, b = blockIdx.z;
  const int tid = threadIdx.x;
  const int c4 = (tid & 15) * 4;
  const int tr = tid >> 4;
  float g4[4], b4[4];
#pragma unroll
  for (int q = 0; q < 4; ++q) { g4[q] = g[cc0 + c4 + q]; b4[q] = be[cc0 + c4 + q]; }
#pragma unroll
  for (int it = 0; it < 4; ++it) {
    const int tt = tr + it * 16;
    const int row = b * 1024 + t0 + tt;
    const size_t base = (size_t)row * 512 + cc0 + c4;
    ushort4v u0 = *(const ushort4v*)&x2T[base];
    ushort4v u1 = *(const ushort4v*)&c2p[base];
    ushort4v u2 = *(const ushort4v*)&c2p[S + base];
    ushort4v u3 = *(const ushort4v*)&c2p[2 * S + base];
    ushort4v u4 = *(const ushort4v*)&c2p[3 * S + base];
    const float2 s = mr[row];
#pragma unroll
    for (int q = 0; q < 4; ++q) {
      const float v = bf2f(u0[q]) + bf2f(u1[q]) + bf2f(u2[q]) + bf2f(u3[q]) + bf2f(u4[q]);
      tile[tt][c4 + q] = (v - s.x) * s.y * g4[q] + b4[q];
    }
  }
  __syncthreads();
  const int tx = tid & 63, cg = tid >> 6;
#pragma unroll
  for (int c = cg; c < 64; c += 4)
    out[((size_t)b * 512 + cc0 + c) * 1024 + t0 + tx] = tile[tx][c];
}

// ---------------------------------------------------------------------------
extern "C" void kernel_launch(void* const* d_in, const int* in_sizes, int n_in,
                              void* d_out, int out_size, void* d_ws, size_t ws_size,
                              hipStream_t stream) {
  (void)in_sizes; (void)n_in; (void)out_size; (void)ws_size;
  const float* x   = (const float*)d_in[0];
  const float* xm  = (const float*)d_in[1];
  const float* am  = (const float*)d_in[2];
  const float* wq  = (const float*)d_in[3];
  const float* bq  = (const float*)d_in[4];
  const float* wk  = (const float*)d_in[5];
  const float* bk  = (const float*)d_in[6];
  const float* wv  = (const float*)d_in[7];
  const float* bv  = (const float*)d_in[8];
  const float* wo  = (const float*)d_in[9];
  const float* bo  = (const float*)d_in[10];
  const float* w1  = (const float*)d_in[11];
  const float* b1  = (const float*)d_in[12];
  const float* w2  = (const float*)d_in[13];
  const float* b2  = (const float*)d_in[14];
  const float* g1  = (const float*)d_in[15];
  const float* be1 = (const float*)d_in[16];
  const float* g2  = (const float*)d_in[17];
  const float* be2 = (const float*)d_in[18];
  float* out = (float*)d_out;

  char* ws = (char*)d_ws;
  size_t off = 0;
  auto alloc = [&](size_t bytes) { char* p = ws + off; off += (bytes + 255) & ~(size_t)255; return p; };

  u16*   wqkv = (u16*)  alloc((size_t)1536 * 512 * 2);
  u16*   wob  = (u16*)  alloc((size_t)512 * 512 * 2);
  u16*   w1p  = (u16*)  alloc((size_t)2048 * 1536 * 2);
  u16*   w2p  = (u16*)  alloc((size_t)512 * 6144 * 2);
  float* bqkv = (float*)alloc(1536 * 4);
  float* ctab = (float*)alloc(1024 * 16 * 4);
  float* stab = (float*)alloc(1024 * 16 * 4);
  unsigned* mbits = (unsigned*)alloc((size_t)8 * 1024 * 32 * 4);
  float2* mr  = (float2*)alloc((size_t)8192 * 8);
  u16*   x2T  = (u16*)  alloc((size_t)8 * 1024 * 512 * 2);   // LN1 out (B,T,C)
  u16*   x2p  = (u16*)  alloc((size_t)8 * 1026 * 512 * 2);   // LN1 out masked, padded
  u16*   h1p  = (u16*)  alloc((size_t)8 * 1026 * 2048 * 2);  // conv1 out, padded (B,1026,F)
  u16*   y1T  = (u16*)  alloc((size_t)8 * 1024 * 512 * 2);   // attn out (B,T,C)
  u16*   xbT  = (u16*)  alloc((size_t)8 * 1024 * 512 * 2);   // masked x^T (B,T,C)
  u16*   oT   = (u16*)  alloc((size_t)8 * 1024 * 512 * 2);   // attn O (B,T,C)
  u16*   qkv3 = (u16*)  alloc((size_t)3 * 8 * 8 * 1024 * 64 * 2); // q,k,v
  u16*   c2p  = (u16*)  alloc((size_t)4 * 8 * 1024 * 512 * 2);    // conv2 partials (4,B,T,C)

  u16* qb = qkv3;
  u16* kb = qkv3 + (size_t)8 * 8 * 1024 * 64;
  u16* vb = kb   + (size_t)8 * 8 * 1024 * 64;

  dim3 blk(256);

  // fused prep (weights, bias, rope, mask bits, pad rows) — one dispatch
  k_prep<<<dim3(29793), blk, 0, stream>>>(
      wq, wk, wv, wo, w1, w2, bq, bk, bv, am,
      wqkv, wob, w1p, w2p, bqkv, ctab, stab, mbits, x2p, h1p);

  // x^T (masked, bf16)
  k_tcvt<<<dim3(8, 16, 8), blk, 0, stream>>>(x, xbT, xm, 512, 1024);

  // QKV projection + bias + rope + head scatter  (flat N=8192, BN=128)
  k_cgemm<0, 128, 0><<<dim3(12, 64), blk, 0, stream>>>(
      wqkv, 512, xbT, 512, 512, qb, kb, vb, bqkv, ctab, stab, nullptr);

  // fused flash attention -> oT (B,T,C)
  k_fattn<<<dim3(8, 64), blk, 0, stream>>>(qb, kb, vb, mbits, oT);

  // y1 = wo o + bo -> y1T (B,T,C)
  k_cgemm<3, 64, 0><<<dim3(4, 128), blk, 0, stream>>>(
      wob, 512, oT, 512, 512, y1T, nullptr, nullptr, bo, nullptr, nullptr, nullptr);

  // LN1 rows -> x2T (residual) + x2p (masked, padded conv input)
  k_ln1<<<dim3(2048), blk, 0, stream>>>(xbT, y1T, xm, g1, be1, x2T, x2p);

  // conv path (tap-shifted padded activations)
  k_cgemm<4, 128, 512><<<dim3(16, 64), blk, 0, stream>>>(
      w1p, 1536, x2p, 0, 1536, h1p, nullptr, nullptr, b1, nullptr, nullptr, xm);
  // conv2: BN=128, split-K x4 (K-slice 1536 each) -> contiguous partials c2p
  k_cgemm<5, 128, 2048><<<dim3(4, 64, 4), blk, 0, stream>>>(
      w2p, 6144, h1p, 0, 1536, c2p, nullptr, nullptr, b2, nullptr, nullptr, xm);

  // LN2: stats then transpose-normalize -> out (B,C,T) fp32
  k_ln2_stats<<<dim3(2048), blk, 0, stream>>>(x2T, c2p, mr);
  k_ln2_write<<<dim3(8, 16, 8), blk, 0, stream>>>(x2T, c2p, mr, g2, be2, out);
}

// Round 12
// 307.951 us; speedup vs baseline: 1.0737x; 1.0737x over previous
//
#include <hip/hip_runtime.h>

typedef unsigned short u16;
typedef __attribute__((ext_vector_type(4))) float floatx4;
typedef __attribute__((ext_vector_type(8))) __bf16 bf16x8;
typedef __attribute__((ext_vector_type(4))) unsigned short ushort4v;
typedef __attribute__((ext_vector_type(8))) unsigned short ushort8v;

#define DI __device__ __forceinline__

// ---- problem constants ----
// B=8, C=512, T=1024, H=8, F=2048, KS=3, head dim 64, ROPE_D=32, EPS=1e-4

DI u16 f2bf(float f) {
  union { float f; unsigned u; } v; v.f = f;
  unsigned r = v.u + 0x7fffu + ((v.u >> 16) & 1u);
  return (u16)(r >> 16);
}
DI float bf2f(u16 h) {
  union { unsigned u; float f; } v; v.u = ((unsigned)h) << 16;
  return v.f;
}

#define GLDS(g, l) __builtin_amdgcn_global_load_lds( \
    (const __attribute__((address_space(1))) unsigned int*)(g), \
    (__attribute__((address_space(3))) unsigned int*)(l), 16, 0, 0)

// ---------------------------------------------------------------------------
// Flash attention (R9 structure, unchanged).
// ---------------------------------------------------------------------------
__global__ __launch_bounds__(256, 2) void k_fattn(
    const u16* __restrict__ qb, const u16* __restrict__ kb,
    const u16* __restrict__ vb, const unsigned* __restrict__ mb,
    u16* __restrict__ oT)
{
  __shared__ __align__(16) u16 Ps[4][32 * 64];
  const int tid  = threadIdx.x;
  const int wave = tid >> 6, lane = tid & 63;
  const int lr = lane & 15, kg = lane >> 4;
  const int qt = blockIdx.x, bh = blockIdx.y;
  const int bb = bh >> 3, hh = bh & 7;
  const int wq0 = qt * 128 + wave * 32;
  const float L2E = 1.44269504f;

  const u16* Qp = qb + (size_t)bh * 65536;
  const u16* Kp = kb + (size_t)bh * 65536;
  const u16* Vp = vb + (size_t)bh * 65536;
  u16* Pw = &Ps[wave][0];

  bf16x8 qf[2][2];
#pragma unroll
  for (int i = 0; i < 2; ++i)
#pragma unroll
    for (int h = 0; h < 2; ++h)
      qf[i][h] = *(const bf16x8*)&Qp[(wq0 + i * 16 + lr) * 64 + h * 32 + kg * 8];

  float l_b[2] = {0.f, 0.f};
  floatx4 o_acc[2][4];
#pragma unroll
  for (int i = 0; i < 2; ++i)
#pragma unroll
    for (int j = 0; j < 4; ++j) o_acc[i][j] = (floatx4){0.f, 0.f, 0.f, 0.f};

  bf16x8 kf[4][2], vf[4][2];
#pragma unroll
  for (int a = 0; a < 4; ++a)
#pragma unroll
    for (int h = 0; h < 2; ++h)
      kf[a][h] = *(const bf16x8*)&Kp[(a * 16 + lr) * 64 + h * 32 + kg * 8];

  for (int it = 0; it < 16; ++it) {
    const int s0 = it * 64;
    unsigned mw[2][2];
#pragma unroll
    for (int b = 0; b < 2; ++b) {
      const size_t rw = ((size_t)bb << 15) + ((size_t)(wq0 + b * 16 + lr) << 5) + (s0 >> 5);
      mw[b][0] = mb[rw]; mw[b][1] = mb[rw + 1];
    }
    floatx4 sT[4][2];
    __builtin_amdgcn_s_setprio(1);
#pragma unroll
    for (int a = 0; a < 4; ++a) {
      sT[a][0] = (floatx4){0.f, 0.f, 0.f, 0.f};
      sT[a][1] = (floatx4){0.f, 0.f, 0.f, 0.f};
#pragma unroll
      for (int b = 0; b < 2; ++b)
#pragma unroll
        for (int h = 0; h < 2; ++h)
          sT[a][b] = __builtin_amdgcn_mfma_f32_16x16x32_bf16(kf[a][h], qf[b][h], sT[a][b], 0, 0, 0);
    }
    __builtin_amdgcn_s_setprio(0);
#pragma unroll
    for (int a = 0; a < 4; ++a)
#pragma unroll
      for (int h = 0; h < 2; ++h)
        vf[a][h] = *(const bf16x8*)&Vp[(a * 16 + lr) * 1024 + s0 + h * 32 + kg * 8];
    if (it < 15) {
      const int sn = s0 + 64;
#pragma unroll
      for (int a = 0; a < 4; ++a)
#pragma unroll
        for (int h = 0; h < 2; ++h)
          kf[a][h] = *(const bf16x8*)&Kp[(sn + a * 16 + lr) * 64 + h * 32 + kg * 8];
    }
#pragma unroll
    for (int b = 0; b < 2; ++b) {
      float sum = 0.f;
#pragma unroll
      for (int a = 0; a < 4; ++a)
#pragma unroll
        for (int r = 0; r < 4; ++r) {
          const int sl = a * 16 + kg * 4 + r;
          float sv = sT[a][b][r] * 0.125f;
          const unsigned wsel = (sl & 32) ? mw[b][1] : mw[b][0];
          if (!((wsel >> (sl & 31)) & 1u)) sv = -10000.f;
          const float p = exp2f(sv * L2E);
          sT[a][b][r] = p;
          sum += p;
        }
      sum += __shfl_xor(sum, 16);
      sum += __shfl_xor(sum, 32);
      l_b[b] += sum;
#pragma unroll
      for (int a = 0; a < 4; ++a) {
        ushort4v pk;
#pragma unroll
        for (int r = 0; r < 4; ++r) {
          __bf16 hv = (__bf16)sT[a][b][r];
          pk[r] = *(u16*)&hv;
        }
        const int sl0 = a * 16 + kg * 4;
        *(ushort4v*)&Pw[(b * 16 + lr) * 64 + (sl0 ^ ((lr & 7) << 3))] = pk;
      }
    }
    asm volatile("s_waitcnt lgkmcnt(0)" ::: "memory");
    __builtin_amdgcn_sched_barrier(0);
    bf16x8 pa[2][2];
#pragma unroll
    for (int i = 0; i < 2; ++i)
#pragma unroll
      for (int h = 0; h < 2; ++h)
        pa[i][h] = *(const bf16x8*)&Pw[(i * 16 + lr) * 64 + (((h * 4 + kg) ^ (lr & 7)) << 3)];
    __builtin_amdgcn_s_setprio(1);
#pragma unroll
    for (int jd = 0; jd < 4; ++jd)
#pragma unroll
      for (int i = 0; i < 2; ++i)
#pragma unroll
        for (int h = 0; h < 2; ++h)
          o_acc[i][jd] = __builtin_amdgcn_mfma_f32_16x16x32_bf16(pa[i][h], vf[jd][h], o_acc[i][jd], 0, 0, 0);
    __builtin_amdgcn_s_setprio(0);
  }
  float linv[2][4];
#pragma unroll
  for (int i = 0; i < 2; ++i)
#pragma unroll
    for (int r = 0; r < 4; ++r) linv[i][r] = 1.f / __shfl(l_b[i], kg * 4 + r);
#pragma unroll
  for (int i = 0; i < 2; ++i)
#pragma unroll
    for (int jd = 0; jd < 4; ++jd)
#pragma unroll
      for (int r = 0; r < 4; ++r) {
        const int t = wq0 + i * 16 + kg * 4 + r;
        const int c = hh * 64 + jd * 16 + lr;
        oT[((size_t)bb * 1024 + t) * 512 + c] = f2bf(o_acc[i][jd][r] * linv[i][r]);
      }
}

// ---------------------------------------------------------------------------
// Flat GEMM, gemm_bt form, XCD-swizzled, BK=64. R12: back to R10's proven
// single-buffer 2-barrier loop; ALL staging addresses hoisted out of the
// K-loop (8 per-thread pointers, compile-time indexed -> registers; inner
// loop is GLDS(ptr + k0)). Conv tap addressing ELIMINATED: in the padded
// (B,1026,F) layout the im2col row is contiguous — B[bt,k] = pad[(b*1026+t)*F
// + k] for k in [0,3F) — so TAPK only affects the per-thread base.
// Both-sides chunk swizzle retained (bank conflicts = 0).
// MODE 0=QKV(+bias+rope+scatter) 3=oproj(+bias -> y1T (B,T,C))
// MODE 4=conv1(relu*mask -> padded h1)
// MODE 5=conv2 split-K partial z -> o0 + z*(B*T*C), bias on z==0, *mask
// ---------------------------------------------------------------------------
template<int MODE, int BN, int TAPK>
__global__ __launch_bounds__(256) void k_cgemm(
    const u16* __restrict__ A, int lda,
    const u16* __restrict__ Bsrc, int ldb,
    int K,
    u16* __restrict__ o0, u16* __restrict__ o1, u16* __restrict__ o2,
    const float* __restrict__ bias,
    const float* __restrict__ ctab, const float* __restrict__ stab,
    const float* __restrict__ msk)
{
  constexpr int BM = 128;
  constexpr int FN = BN / 32;
  __shared__ __align__(16) u16 As[2 * BM * 32];
  __shared__ __align__(16) u16 Bs[2 * BN * 32];

  const int tid  = threadIdx.x;
  const int wave = tid >> 6, lane = tid & 63;
  const int wm = wave >> 1, wn = wave & 1;
  const int lr = lane & 15, kg = lane >> 4;

  // XCD-aware bijective swizzle (nwg % 8 == 0 for all our grids)
  const int nwg = gridDim.x * gridDim.y;
  const int h0  = blockIdx.y * gridDim.x + blockIdx.x;
  const int cpx = nwg >> 3;
  const int tl  = (h0 & 7) * cpx + (h0 >> 3);
  const int bx  = tl % gridDim.x;
  const int by  = tl / gridDim.x;

  const int m0 = bx * BM, n0 = by * BN;
  const int koff = blockIdx.z * K;

  // ---- per-thread staging pointers, hoisted out of the K-loop ----
  const u16* aP[2][BM / 64];
  const u16* bP[2][BN / 64];
#pragma unroll
  for (int h = 0; h < 2; ++h) {
#pragma unroll
    for (int ch = 0; ch < BM / 64; ++ch) {
      const int idx = ch * 256 + tid;
      const int row = idx >> 2;
      const int kk = (((idx & 3) ^ ((row >> 1) & 3)) << 3);   // source pre-swizzle
      aP[h][ch] = A + (size_t)(m0 + row) * lda + koff + h * 32 + kk;
    }
#pragma unroll
    for (int ch = 0; ch < BN / 64; ++ch) {
      const int idx = ch * 256 + tid;
      const int row = idx >> 2;
      const int kk = (((idx & 3) ^ ((row >> 1) & 3)) << 3);
      const int bt = n0 + row;
      size_t rowbase;
      if constexpr (TAPK == 0) {
        rowbase = (size_t)bt * ldb;
      } else {
        const int b = bt >> 10, t = bt & 1023;
        rowbase = ((size_t)(b * 1026 + t)) * TAPK;   // contiguous im2col row
      }
      bP[h][ch] = Bsrc + rowbase + koff + h * 32 + kk;
    }
  }

  floatx4 acc[4][FN];
#pragma unroll
  for (int i = 0; i < 4; ++i)
#pragma unroll
    for (int j = 0; j < FN; ++j) acc[i][j] = (floatx4){0.f, 0.f, 0.f, 0.f};

  const int csw = (kg ^ ((lr >> 1) & 3)) * 8;   // read-side chunk swizzle

  for (int k0 = 0; k0 < K; k0 += 64) {
#pragma unroll
    for (int h = 0; h < 2; ++h) {
#pragma unroll
      for (int ch = 0; ch < BM / 64; ++ch)
        GLDS(aP[h][ch] + k0, &As[h * BM * 32 + (ch * 256 + tid) * 8]);
#pragma unroll
      for (int ch = 0; ch < BN / 64; ++ch)
        GLDS(bP[h][ch] + k0, &Bs[h * BN * 32 + (ch * 256 + tid) * 8]);
    }
    __syncthreads();
    bf16x8 af[2][4], bfr[2][FN];
#pragma unroll
    for (int h = 0; h < 2; ++h) {
#pragma unroll
      for (int i = 0; i < 4; ++i)
        af[h][i] = *(const bf16x8*)&As[(h * BM + wm * 64 + i * 16 + lr) * 32 + csw];
#pragma unroll
      for (int j = 0; j < FN; ++j)
        bfr[h][j] = *(const bf16x8*)&Bs[(h * BN + wn * (BN / 2) + j * 16 + lr) * 32 + csw];
    }
#pragma unroll
    for (int h = 0; h < 2; ++h)
#pragma unroll
      for (int i = 0; i < 4; ++i)
#pragma unroll
        for (int j = 0; j < FN; ++j)
          acc[i][j] = __builtin_amdgcn_mfma_f32_16x16x32_bf16(af[h][i], bfr[h][j], acc[i][j], 0, 0, 0);
    __syncthreads();
  }

  const int wrow0 = m0 + wm * 64;
  const int col0  = n0 + wn * (BN / 2);

  if constexpr (MODE == 0) {  // ---- QKV: bias + RoPE + scatter ----
    float v[4][FN][4];
#pragma unroll
    for (int i = 0; i < 4; ++i)
#pragma unroll
      for (int j = 0; j < FN; ++j)
#pragma unroll
        for (int r = 0; r < 4; ++r)
          v[i][j][r] = acc[i][j][r] + bias[wrow0 + i * 16 + kg * 4 + r];
    const int sec = wrow0 >> 9;            // 0=q 1=k 2=v
    const int hh  = (wrow0 & 511) >> 6;    // head
    if (sec < 2) {
#pragma unroll
      for (int j = 0; j < FN; ++j) {
        const int t = (col0 + j * 16 + lr) & 1023;
#pragma unroll
        for (int r = 0; r < 4; ++r) {
          const int a = kg * 4 + r;
          const float cv = ctab[t * 16 + a], sv = stab[t * 16 + a];
          const float a0 = v[0][j][r], a1 = v[1][j][r];
          v[0][j][r] = a0 * cv - a1 * sv;
          v[1][j][r] = a1 * cv + a0 * sv;
        }
      }
      u16* dst = (sec == 0) ? o0 : o1;     // q,k: (B,H,T,64)
#pragma unroll
      for (int i = 0; i < 4; ++i)
#pragma unroll
        for (int j = 0; j < FN; ++j) {
          const int bt = col0 + j * 16 + lr;
          const int b = bt >> 10, t = bt & 1023;
          ushort4v pk;
#pragma unroll
          for (int r = 0; r < 4; ++r) pk[r] = f2bf(v[i][j][r]);
          *(ushort4v*)&dst[(((size_t)b * 8 + hh) * 1024 + t) * 64 + i * 16 + kg * 4] = pk;
        }
    } else {                               // v: (B,H,64,T)
#pragma unroll
      for (int i = 0; i < 4; ++i)
#pragma unroll
        for (int j = 0; j < FN; ++j) {
          const int bt = col0 + j * 16 + lr;
          const int b = bt >> 10, t = bt & 1023;
#pragma unroll
          for (int r = 0; r < 4; ++r) {
            const int dk = i * 16 + kg * 4 + r;
            o2[(((size_t)b * 8 + hh) * 64 + dk) * 1024 + t] = f2bf(v[i][j][r]);
          }
        }
    }
  } else if constexpr (MODE == 3) {  // ---- O-proj: +bias -> y1T (B,T,C) ----
#pragma unroll
    for (int i = 0; i < 4; ++i)
#pragma unroll
      for (int j = 0; j < FN; ++j) {
        const int bt = col0 + j * 16 + lr;
        const int c0 = wrow0 + i * 16 + kg * 4;
        ushort4v pk;
#pragma unroll
        for (int r = 0; r < 4; ++r) pk[r] = f2bf(acc[i][j][r] + bias[c0 + r]);
        *(ushort4v*)&o0[(size_t)bt * 512 + c0] = pk;
      }
  } else if constexpr (MODE == 4) {  // ---- conv1: relu(acc+b1)*mask -> h1pad ----
#pragma unroll
    for (int i = 0; i < 4; ++i) {
      const int r0 = wrow0 + i * 16 + kg * 4;
#pragma unroll
      for (int j = 0; j < FN; ++j) {
        const int bt = col0 + j * 16 + lr;
        const int b = bt >> 10, t = bt & 1023;
        const float mv = msk[(size_t)b * 1024 + t];
        ushort4v pk;
#pragma unroll
        for (int r = 0; r < 4; ++r)
          pk[r] = f2bf(fmaxf(acc[i][j][r] + bias[r0 + r], 0.f) * mv);
        *(ushort4v*)&o0[((size_t)(b * 1026 + t + 1)) * 2048 + r0] = pk;
      }
    }
  } else {                           // ---- conv2 split-K partial z -> o0 + z*S ----
    u16* dst = o0 + (size_t)blockIdx.z * 8 * 1024 * 512;
    const bool z0 = (blockIdx.z == 0);
#pragma unroll
    for (int i = 0; i < 4; ++i)
#pragma unroll
      for (int j = 0; j < FN; ++j) {
        const int bt = col0 + j * 16 + lr;
        const int b = bt >> 10, t = bt & 1023;
        const int c0 = wrow0 + i * 16 + kg * 4;
        const float mv = msk[(size_t)b * 1024 + t];
        ushort4v pk;
#pragma unroll
        for (int r = 0; r < 4; ++r) {
          const float bv = z0 ? bias[c0 + r] : 0.f;
          pk[r] = f2bf((acc[i][j][r] + bv) * mv);
        }
        *(ushort4v*)&dst[(size_t)bt * 512 + c0] = pk;
      }
  }
}

// ---------------------------------------------------------------------------
// Fused prep mega-kernel (unchanged from R10).
// ---------------------------------------------------------------------------
__global__ __launch_bounds__(256) void k_prep(
    const float* __restrict__ wq, const float* __restrict__ wk,
    const float* __restrict__ wv, const float* __restrict__ wo,
    const float* __restrict__ w1, const float* __restrict__ w2,
    const float* __restrict__ bq, const float* __restrict__ bk,
    const float* __restrict__ bv, const float* __restrict__ am,
    u16* __restrict__ wqkv, u16* __restrict__ wob,
    u16* __restrict__ w1p, u16* __restrict__ w2p,
    float* __restrict__ bqkv, float* __restrict__ ctab, float* __restrict__ stab,
    unsigned* __restrict__ mbits, u16* __restrict__ x2p, u16* __restrict__ h1p)
{
  const int bid = blockIdx.x;
  if (bid < 4096) {
    const int seg = bid >> 10;
    const int i = (bid & 1023) * 256 + threadIdx.x;
    const float* src = (seg == 0) ? wq : (seg == 1) ? wk : (seg == 2) ? wv : wo;
    u16* dst = (seg < 3) ? (wqkv + (size_t)seg * 512 * 512) : wob;
    dst[i] = f2bf(src[i]);
  } else if (bid < 16384) {
    const int i = (bid - 4096) * 256 + threadIdx.x;
    const int f = i / 1536, rem = i % 1536;
    const int kk = rem >> 9, c = rem & 511;
    w1p[i] = f2bf(w1[f * 1536 + c * 3 + kk]);
  } else if (bid < 28672) {
    const int i = (bid - 16384) * 256 + threadIdx.x;
    const int c = i / 6144, rem = i % 6144;
    const int kk = rem >> 11, f = rem & 2047;
    w2p[i] = f2bf(w2[c * 6144 + f * 3 + kk]);
  } else if (bid < 29696) {
    const int i = (bid - 28672) * 256 + threadIdx.x;
    const float* src = am + (size_t)i * 32;
    unsigned w = 0;
#pragma unroll
    for (int q = 0; q < 32; ++q) w |= (src[q] != 0.f) ? (1u << q) : 0u;
    mbits[i] = w;
  } else if (bid < 29760) {
    const int i = (bid - 29696) * 256 + threadIdx.x;
    const int t = i >> 4, a = i & 15;
    const float theta = powf(10000.f, -(float)a / 16.f);
    const float ang = (float)t * theta;
    ctab[i] = cosf(ang);
    stab[i] = sinf(ang);
  } else if (bid == 29760) {
    for (int i = threadIdx.x; i < 1536; i += 256)
      bqkv[i] = (i < 512) ? bq[i] : (i < 1024) ? bk[i - 512] : bv[i - 1024];
  } else {
    int zb = bid - 29761;
    if (zb < 16) {
      const int b = zb >> 1;
      const size_t row = (zb & 1) ? 1025 : 0;
      u16* r = x2p + ((size_t)b * 1026 + row) * 512;
      for (int i = threadIdx.x; i < 512; i += 256) r[i] = 0;
    } else {
      zb -= 16;
      const int b = zb >> 1;
      const size_t row = (zb & 1) ? 1025 : 0;
      u16* r = h1p + ((size_t)b * 1026 + row) * 2048;
      for (int i = threadIdx.x; i < 2048; i += 256) r[i] = 0;
    }
  }
}

// tiled fp32 (B,R,TT) -> bf16 (B,TT,R) transpose-convert, column mask applied
__global__ __launch_bounds__(256) void k_tcvt(const float* __restrict__ in, u16* __restrict__ out,
                                              const float* __restrict__ msk, int R, int TT) {
  __shared__ u16 tile[64][65];
  const int b = blockIdx.z;
  const int r0 = blockIdx.x * 64, t0 = blockIdx.y * 64;
  const int tx = threadIdx.x & 63, ty = threadIdx.x >> 6;
  const float mv = msk ? msk[(size_t)b * TT + t0 + tx] : 1.f;
  const float* ib = in + (size_t)b * R * TT;
#pragma unroll
  for (int rr = ty; rr < 64; rr += 4)
    tile[rr][tx] = f2bf(ib[(size_t)(r0 + rr) * TT + t0 + tx] * mv);
  __syncthreads();
  u16* ob = out + (size_t)b * TT * R;
#pragma unroll
  for (int tt = ty; tt < 64; tt += 4)
    ob[(size_t)(t0 + tt) * R + r0 + tx] = tile[tx][tt];
}

// LN1: one wave per (b,t) row of 512. r = xbT + y1T (both (B,T,C) bf16).
__global__ __launch_bounds__(256) void k_ln1(
    const u16* __restrict__ xbT, const u16* __restrict__ y1T,
    const float* __restrict__ xm, const float* __restrict__ g,
    const float* __restrict__ be, u16* __restrict__ x2T, u16* __restrict__ x2p)
{
  const int lane = threadIdx.x & 63, wv = threadIdx.x >> 6;
  const int row = blockIdx.x * 4 + wv;          // b*1024 + t
  const int b = row >> 10, t = row & 1023;
  const size_t base = (size_t)row * 512 + lane * 8;
  ushort8v ux = *(const ushort8v*)&xbT[base];
  ushort8v uy = *(const ushort8v*)&y1T[base];
  float v[8];
  float sum = 0.f, ss = 0.f;
#pragma unroll
  for (int q = 0; q < 8; ++q) {
    v[q] = bf2f(ux[q]) + bf2f(uy[q]);
    sum += v[q]; ss += v[q] * v[q];
  }
#pragma unroll
  for (int o = 32; o; o >>= 1) { sum += __shfl_xor(sum, o); ss += __shfl_xor(ss, o); }
  const float mean = sum * (1.f / 512.f);
  const float var  = ss * (1.f / 512.f) - mean * mean;
  const float rs   = rsqrtf(var + 1e-4f);
  const float m    = xm[(size_t)b * 1024 + t];
  ushort8v on, om;
#pragma unroll
  for (int q = 0; q < 8; ++q) {
    const int c = lane * 8 + q;
    const float nv = (v[q] - mean) * rs * g[c] + be[c];
    on[q] = f2bf(nv);
    om[q] = f2bf(nv * m);
  }
  *(ushort8v*)&x2T[base] = on;
  *(ushort8v*)&x2p[((size_t)(b * 1026 + t + 1)) * 512 + lane * 8] = om;
}

// LN2 stats: one wave per row; r = x2T + sum of 4 conv2 partials
__global__ __launch_bounds__(256) void k_ln2_stats(
    const u16* __restrict__ x2T, const u16* __restrict__ c2p,
    float2* __restrict__ mr)
{
  constexpr size_t S = (size_t)8 * 1024 * 512;
  const int lane = threadIdx.x & 63, wv = threadIdx.x >> 6;
  const int row = blockIdx.x * 4 + wv;
  const size_t base = (size_t)row * 512 + lane * 8;
  ushort8v u0 = *(const ushort8v*)&x2T[base];
  ushort8v u1 = *(const ushort8v*)&c2p[base];
  ushort8v u2 = *(const ushort8v*)&c2p[S + base];
  ushort8v u3 = *(const ushort8v*)&c2p[2 * S + base];
  ushort8v u4 = *(const ushort8v*)&c2p[3 * S + base];
  float sum = 0.f, ss = 0.f;
#pragma unroll
  for (int q = 0; q < 8; ++q) {
    const float v = bf2f(u0[q]) + bf2f(u1[q]) + bf2f(u2[q]) + bf2f(u3[q]) + bf2f(u4[q]);
    sum += v; ss += v * v;
  }
#pragma unroll
  for (int o = 32; o; o >>= 1) { sum += __shfl_xor(sum, o); ss += __shfl_xor(ss, o); }
  if (lane == 0) {
    const float mean = sum * (1.f / 512.f);
    const float var  = ss * (1.f / 512.f) - mean * mean;
    mr[row] = (float2){mean, rsqrtf(var + 1e-4f)};
  }
}

// LN2 write: normalize + transpose to out (B,C,T) fp32.
__global__ __launch_bounds__(256) void k_ln2_write(
    const u16* __restrict__ x2T, const u16* __restrict__ c2p,
    const float2* __restrict__ mr,
    const float* __restrict__ g, const float* __restrict__ be,
    float* __restrict__ out)
{
  constexpr size_t S = (size_t)8 * 1024 * 512;
  __shared__ float tile[64][65];
  const int cc0 = blockIdx.x * 64, t0 = blockIdx.y * 64, b = blockIdx.z;
  const int tid = threadIdx.x;
  const int c4 = (tid & 15) * 4;
  const int tr = tid >> 4;
  float g4[4], b4[4];
#pragma unroll
  for (int q = 0; q < 4; ++q) { g4[q] = g[cc0 + c4 + q]; b4[q] = be[cc0 + c4 + q]; }
#pragma unroll
  for (int it = 0; it < 4; ++it) {
    const int tt = tr + it * 16;
    const int row = b * 1024 + t0 + tt;
    const size_t base = (size_t)row * 512 + cc0 + c4;
    ushort4v u0 = *(const ushort4v*)&x2T[base];
    ushort4v u1 = *(const ushort4v*)&c2p[base];
    ushort4v u2 = *(const ushort4v*)&c2p[S + base];
    ushort4v u3 = *(const ushort4v*)&c2p[2 * S + base];
    ushort4v u4 = *(const ushort4v*)&c2p[3 * S + base];
    const float2 s = mr[row];
#pragma unroll
    for (int q = 0; q < 4; ++q) {
      const float v = bf2f(u0[q]) + bf2f(u1[q]) + bf2f(u2[q]) + bf2f(u3[q]) + bf2f(u4[q]);
      tile[tt][c4 + q] = (v - s.x) * s.y * g4[q] + b4[q];
    }
  }
  __syncthreads();
  const int tx = tid & 63, cg = tid >> 6;
#pragma unroll
  for (int c = cg; c < 64; c += 4)
    out[((size_t)b * 512 + cc0 + c) * 1024 + t0 + tx] = tile[tx][c];
}

// ---------------------------------------------------------------------------
extern "C" void kernel_launch(void* const* d_in, const int* in_sizes, int n_in,
                              void* d_out, int out_size, void* d_ws, size_t ws_size,
                              hipStream_t stream) {
  (void)in_sizes; (void)n_in; (void)out_size; (void)ws_size;
  const float* x   = (const float*)d_in[0];
  const float* xm  = (const float*)d_in[1];
  const float* am  = (const float*)d_in[2];
  const float* wq  = (const float*)d_in[3];
  const float* bq  = (const float*)d_in[4];
  const float* wk  = (const float*)d_in[5];
  const float* bk  = (const float*)d_in[6];
  const float* wv  = (const float*)d_in[7];
  const float* bv  = (const float*)d_in[8];
  const float* wo  = (const float*)d_in[9];
  const float* bo  = (const float*)d_in[10];
  const float* w1  = (const float*)d_in[11];
  const float* b1  = (const float*)d_in[12];
  const float* w2  = (const float*)d_in[13];
  const float* b2  = (const float*)d_in[14];
  const float* g1  = (const float*)d_in[15];
  const float* be1 = (const float*)d_in[16];
  const float* g2  = (const float*)d_in[17];
  const float* be2 = (const float*)d_in[18];
  float* out = (float*)d_out;

  char* ws = (char*)d_ws;
  size_t off = 0;
  auto alloc = [&](size_t bytes) { char* p = ws + off; off += (bytes + 255) & ~(size_t)255; return p; };

  u16*   wqkv = (u16*)  alloc((size_t)1536 * 512 * 2);
  u16*   wob  = (u16*)  alloc((size_t)512 * 512 * 2);
  u16*   w1p  = (u16*)  alloc((size_t)2048 * 1536 * 2);
  u16*   w2p  = (u16*)  alloc((size_t)512 * 6144 * 2);
  float* bqkv = (float*)alloc(1536 * 4);
  float* ctab = (float*)alloc(1024 * 16 * 4);
  float* stab = (float*)alloc(1024 * 16 * 4);
  unsigned* mbits = (unsigned*)alloc((size_t)8 * 1024 * 32 * 4);
  float2* mr  = (float2*)alloc((size_t)8192 * 8);
  u16*   x2T  = (u16*)  alloc((size_t)8 * 1024 * 512 * 2);   // LN1 out (B,T,C)
  u16*   x2p  = (u16*)  alloc((size_t)8 * 1026 * 512 * 2);   // LN1 out masked, padded
  u16*   h1p  = (u16*)  alloc((size_t)8 * 1026 * 2048 * 2);  // conv1 out, padded (B,1026,F)
  u16*   y1T  = (u16*)  alloc((size_t)8 * 1024 * 512 * 2);   // attn out (B,T,C)
  u16*   xbT  = (u16*)  alloc((size_t)8 * 1024 * 512 * 2);   // masked x^T (B,T,C)
  u16*   oT   = (u16*)  alloc((size_t)8 * 1024 * 512 * 2);   // attn O (B,T,C)
  u16*   qkv3 = (u16*)  alloc((size_t)3 * 8 * 8 * 1024 * 64 * 2); // q,k,v
  u16*   c2p  = (u16*)  alloc((size_t)4 * 8 * 1024 * 512 * 2);    // conv2 partials (4,B,T,C)

  u16* qb = qkv3;
  u16* kb = qkv3 + (size_t)8 * 8 * 1024 * 64;
  u16* vb = kb   + (size_t)8 * 8 * 1024 * 64;

  dim3 blk(256);

  // fused prep (weights, bias, rope, mask bits, pad rows) — one dispatch
  k_prep<<<dim3(29793), blk, 0, stream>>>(
      wq, wk, wv, wo, w1, w2, bq, bk, bv, am,
      wqkv, wob, w1p, w2p, bqkv, ctab, stab, mbits, x2p, h1p);

  // x^T (masked, bf16)
  k_tcvt<<<dim3(8, 16, 8), blk, 0, stream>>>(x, xbT, xm, 512, 1024);

  // QKV projection + bias + rope + head scatter  (flat N=8192, BN=128)
  k_cgemm<0, 128, 0><<<dim3(12, 64), blk, 0, stream>>>(
      wqkv, 512, xbT, 512, 512, qb, kb, vb, bqkv, ctab, stab, nullptr);

  // fused flash attention -> oT (B,T,C)
  k_fattn<<<dim3(8, 64), blk, 0, stream>>>(qb, kb, vb, mbits, oT);

  // y1 = wo o + bo -> y1T (B,T,C)
  k_cgemm<3, 64, 0><<<dim3(4, 128), blk, 0, stream>>>(
      wob, 512, oT, 512, 512, y1T, nullptr, nullptr, bo, nullptr, nullptr, nullptr);

  // LN1 rows -> x2T (residual) + x2p (masked, padded conv input)
  k_ln1<<<dim3(2048), blk, 0, stream>>>(xbT, y1T, xm, g1, be1, x2T, x2p);

  // conv path (contiguous im2col rows in padded layout)
  k_cgemm<4, 128, 512><<<dim3(16, 64), blk, 0, stream>>>(
      w1p, 1536, x2p, 0, 1536, h1p, nullptr, nullptr, b1, nullptr, nullptr, xm);
  // conv2: BN=128, split-K x4 (K-slice 1536 each) -> contiguous partials c2p
  k_cgemm<5, 128, 2048><<<dim3(4, 64, 4), blk, 0, stream>>>(
      w2p, 6144, h1p, 0, 1536, c2p, nullptr, nullptr, b2, nullptr, nullptr, xm);

  // LN2: stats then transpose-normalize -> out (B,C,T) fp32
  k_ln2_stats<<<dim3(2048), blk, 0, stream>>>(x2T, c2p, mr);
  k_ln2_write<<<dim3(8, 16, 8), blk, 0, stream>>>(x2T, c2p, mr, g2, be2, out);
}

// Round 13
// 299.630 us; speedup vs baseline: 1.1035x; 1.0278x over previous
//
#include <hip/hip_runtime.h>

typedef unsigned short u16;
typedef __attribute__((ext_vector_type(4))) float floatx4;
typedef __attribute__((ext_vector_type(8))) __bf16 bf16x8;
typedef __attribute__((ext_vector_type(4))) unsigned short ushort4v;
typedef __attribute__((ext_vector_type(8))) unsigned short ushort8v;

#define DI __device__ __forceinline__

// ---- problem constants ----
// B=8, C=512, T=1024, H=8, F=2048, KS=3, head dim 64, ROPE_D=32, EPS=1e-4

DI u16 f2bf(float f) {
  union { float f; unsigned u; } v; v.f = f;
  unsigned r = v.u + 0x7fffu + ((v.u >> 16) & 1u);
  return (u16)(r >> 16);
}
DI float bf2f(u16 h) {
  union { unsigned u; float f; } v; v.u = ((unsigned)h) << 16;
  return v.f;
}

#define GLDS(g, l) __builtin_amdgcn_global_load_lds( \
    (const __attribute__((address_space(1))) unsigned int*)(g), \
    (__attribute__((address_space(3))) unsigned int*)(l), 16, 0, 0)

// ---------------------------------------------------------------------------
// Flash attention (R9 structure). R13: q pre-scaled by 0.125 at QKV epilogue
// (drops 32 muls/lane/step here); l cross-lane reduce deferred to epilogue.
// ---------------------------------------------------------------------------
__global__ __launch_bounds__(256, 2) void k_fattn(
    const u16* __restrict__ qb, const u16* __restrict__ kb,
    const u16* __restrict__ vb, const unsigned* __restrict__ mb,
    u16* __restrict__ oT)
{
  __shared__ __align__(16) u16 Ps[4][32 * 64];
  const int tid  = threadIdx.x;
  const int wave = tid >> 6, lane = tid & 63;
  const int lr = lane & 15, kg = lane >> 4;
  const int qt = blockIdx.x, bh = blockIdx.y;
  const int bb = bh >> 3, hh = bh & 7;
  const int wq0 = qt * 128 + wave * 32;
  const float L2E = 1.44269504f;

  const u16* Qp = qb + (size_t)bh * 65536;
  const u16* Kp = kb + (size_t)bh * 65536;
  const u16* Vp = vb + (size_t)bh * 65536;
  u16* Pw = &Ps[wave][0];

  bf16x8 qf[2][2];
#pragma unroll
  for (int i = 0; i < 2; ++i)
#pragma unroll
    for (int h = 0; h < 2; ++h)
      qf[i][h] = *(const bf16x8*)&Qp[(wq0 + i * 16 + lr) * 64 + h * 32 + kg * 8];

  float l_b[2] = {0.f, 0.f};
  floatx4 o_acc[2][4];
#pragma unroll
  for (int i = 0; i < 2; ++i)
#pragma unroll
    for (int j = 0; j < 4; ++j) o_acc[i][j] = (floatx4){0.f, 0.f, 0.f, 0.f};

  bf16x8 kf[4][2], vf[4][2];
#pragma unroll
  for (int a = 0; a < 4; ++a)
#pragma unroll
    for (int h = 0; h < 2; ++h)
      kf[a][h] = *(const bf16x8*)&Kp[(a * 16 + lr) * 64 + h * 32 + kg * 8];

  for (int it = 0; it < 16; ++it) {
    const int s0 = it * 64;
    unsigned mw[2][2];
#pragma unroll
    for (int b = 0; b < 2; ++b) {
      const size_t rw = ((size_t)bb << 15) + ((size_t)(wq0 + b * 16 + lr) << 5) + (s0 >> 5);
      mw[b][0] = mb[rw]; mw[b][1] = mb[rw + 1];
    }
    floatx4 sT[4][2];
    __builtin_amdgcn_s_setprio(1);
#pragma unroll
    for (int a = 0; a < 4; ++a) {
      sT[a][0] = (floatx4){0.f, 0.f, 0.f, 0.f};
      sT[a][1] = (floatx4){0.f, 0.f, 0.f, 0.f};
#pragma unroll
      for (int b = 0; b < 2; ++b)
#pragma unroll
        for (int h = 0; h < 2; ++h)
          sT[a][b] = __builtin_amdgcn_mfma_f32_16x16x32_bf16(kf[a][h], qf[b][h], sT[a][b], 0, 0, 0);
    }
    __builtin_amdgcn_s_setprio(0);
#pragma unroll
    for (int a = 0; a < 4; ++a)
#pragma unroll
      for (int h = 0; h < 2; ++h)
        vf[a][h] = *(const bf16x8*)&Vp[(a * 16 + lr) * 1024 + s0 + h * 32 + kg * 8];
    if (it < 15) {
      const int sn = s0 + 64;
#pragma unroll
      for (int a = 0; a < 4; ++a)
#pragma unroll
        for (int h = 0; h < 2; ++h)
          kf[a][h] = *(const bf16x8*)&Kp[(sn + a * 16 + lr) * 64 + h * 32 + kg * 8];
    }
#pragma unroll
    for (int b = 0; b < 2; ++b) {
      float sum = 0.f;
#pragma unroll
      for (int a = 0; a < 4; ++a)
#pragma unroll
        for (int r = 0; r < 4; ++r) {
          const int sl = a * 16 + kg * 4 + r;
          float sv = sT[a][b][r];                 // q pre-scaled by 0.125
          const unsigned wsel = (sl & 32) ? mw[b][1] : mw[b][0];
          if (!((wsel >> (sl & 31)) & 1u)) sv = -10000.f;
          const float p = exp2f(sv * L2E);
          sT[a][b][r] = p;
          sum += p;
        }
      l_b[b] += sum;                              // cross-lane reduce deferred
#pragma unroll
      for (int a = 0; a < 4; ++a) {
        ushort4v pk;
#pragma unroll
        for (int r = 0; r < 4; ++r) {
          __bf16 hv = (__bf16)sT[a][b][r];
          pk[r] = *(u16*)&hv;
        }
        const int sl0 = a * 16 + kg * 4;
        *(ushort4v*)&Pw[(b * 16 + lr) * 64 + (sl0 ^ ((lr & 7) << 3))] = pk;
      }
    }
    asm volatile("s_waitcnt lgkmcnt(0)" ::: "memory");
    __builtin_amdgcn_sched_barrier(0);
    bf16x8 pa[2][2];
#pragma unroll
    for (int i = 0; i < 2; ++i)
#pragma unroll
      for (int h = 0; h < 2; ++h)
        pa[i][h] = *(const bf16x8*)&Pw[(i * 16 + lr) * 64 + (((h * 4 + kg) ^ (lr & 7)) << 3)];
    __builtin_amdgcn_s_setprio(1);
#pragma unroll
    for (int jd = 0; jd < 4; ++jd)
#pragma unroll
      for (int i = 0; i < 2; ++i)
#pragma unroll
        for (int h = 0; h < 2; ++h)
          o_acc[i][jd] = __builtin_amdgcn_mfma_f32_16x16x32_bf16(pa[i][h], vf[jd][h], o_acc[i][jd], 0, 0, 0);
    __builtin_amdgcn_s_setprio(0);
  }
  // epilogue: finish l reduce (linear -> once), divide, store oT (B,T,C)
#pragma unroll
  for (int i = 0; i < 2; ++i) {
    l_b[i] += __shfl_xor(l_b[i], 16);
    l_b[i] += __shfl_xor(l_b[i], 32);
  }
  float linv[2][4];
#pragma unroll
  for (int i = 0; i < 2; ++i)
#pragma unroll
    for (int r = 0; r < 4; ++r) linv[i][r] = 1.f / __shfl(l_b[i], kg * 4 + r);
#pragma unroll
  for (int i = 0; i < 2; ++i)
#pragma unroll
    for (int jd = 0; jd < 4; ++jd)
#pragma unroll
      for (int r = 0; r < 4; ++r) {
        const int t = wq0 + i * 16 + kg * 4 + r;
        const int c = hh * 64 + jd * 16 + lr;
        oT[((size_t)bb * 1024 + t) * 512 + c] = f2bf(o_acc[i][jd][r] * linv[i][r]);
      }
}

// ---------------------------------------------------------------------------
// Flat GEMM, gemm_bt form, XCD-swizzled, BK=64 (R12 structure: single-buffer
// 2-barrier loop, staging pointers hoisted, contiguous im2col rows, both-sides
// chunk swizzle -> 0 bank conflicts).
// MODE 0=QKV(+bias+rope+scatter, q scaled 0.125) 3=oproj(+bias -> y1T)
// MODE 4=conv1(relu*mask -> padded h1)
// MODE 5=conv2 split-K partial z -> o0 + z*(B*T*C), bias on z==0, *mask
// ---------------------------------------------------------------------------
template<int MODE, int BN, int TAPK>
__global__ __launch_bounds__(256) void k_cgemm(
    const u16* __restrict__ A, int lda,
    const u16* __restrict__ Bsrc, int ldb,
    int K,
    u16* __restrict__ o0, u16* __restrict__ o1, u16* __restrict__ o2,
    const float* __restrict__ bias,
    const float* __restrict__ ctab, const float* __restrict__ stab,
    const float* __restrict__ msk)
{
  constexpr int BM = 128;
  constexpr int FN = BN / 32;
  __shared__ __align__(16) u16 As[2 * BM * 32];
  __shared__ __align__(16) u16 Bs[2 * BN * 32];

  const int tid  = threadIdx.x;
  const int wave = tid >> 6, lane = tid & 63;
  const int wm = wave >> 1, wn = wave & 1;
  const int lr = lane & 15, kg = lane >> 4;

  // XCD-aware bijective swizzle (nwg % 8 == 0 for all our grids)
  const int nwg = gridDim.x * gridDim.y;
  const int h0  = blockIdx.y * gridDim.x + blockIdx.x;
  const int cpx = nwg >> 3;
  const int tl  = (h0 & 7) * cpx + (h0 >> 3);
  const int bx  = tl % gridDim.x;
  const int by  = tl / gridDim.x;

  const int m0 = bx * BM, n0 = by * BN;
  const int koff = blockIdx.z * K;

  // ---- per-thread staging pointers, hoisted out of the K-loop ----
  const u16* aP[2][BM / 64];
  const u16* bP[2][BN / 64];
#pragma unroll
  for (int h = 0; h < 2; ++h) {
#pragma unroll
    for (int ch = 0; ch < BM / 64; ++ch) {
      const int idx = ch * 256 + tid;
      const int row = idx >> 2;
      const int kk = (((idx & 3) ^ ((row >> 1) & 3)) << 3);   // source pre-swizzle
      aP[h][ch] = A + (size_t)(m0 + row) * lda + koff + h * 32 + kk;
    }
#pragma unroll
    for (int ch = 0; ch < BN / 64; ++ch) {
      const int idx = ch * 256 + tid;
      const int row = idx >> 2;
      const int kk = (((idx & 3) ^ ((row >> 1) & 3)) << 3);
      const int bt = n0 + row;
      size_t rowbase;
      if constexpr (TAPK == 0) {
        rowbase = (size_t)bt * ldb;
      } else {
        const int b = bt >> 10, t = bt & 1023;
        rowbase = ((size_t)(b * 1026 + t)) * TAPK;   // contiguous im2col row
      }
      bP[h][ch] = Bsrc + rowbase + koff + h * 32 + kk;
    }
  }

  floatx4 acc[4][FN];
#pragma unroll
  for (int i = 0; i < 4; ++i)
#pragma unroll
    for (int j = 0; j < FN; ++j) acc[i][j] = (floatx4){0.f, 0.f, 0.f, 0.f};

  const int csw = (kg ^ ((lr >> 1) & 3)) * 8;   // read-side chunk swizzle

  for (int k0 = 0; k0 < K; k0 += 64) {
#pragma unroll
    for (int h = 0; h < 2; ++h) {
#pragma unroll
      for (int ch = 0; ch < BM / 64; ++ch)
        GLDS(aP[h][ch] + k0, &As[h * BM * 32 + (ch * 256 + tid) * 8]);
#pragma unroll
      for (int ch = 0; ch < BN / 64; ++ch)
        GLDS(bP[h][ch] + k0, &Bs[h * BN * 32 + (ch * 256 + tid) * 8]);
    }
    __syncthreads();
    bf16x8 af[2][4], bfr[2][FN];
#pragma unroll
    for (int h = 0; h < 2; ++h) {
#pragma unroll
      for (int i = 0; i < 4; ++i)
        af[h][i] = *(const bf16x8*)&As[(h * BM + wm * 64 + i * 16 + lr) * 32 + csw];
#pragma unroll
      for (int j = 0; j < FN; ++j)
        bfr[h][j] = *(const bf16x8*)&Bs[(h * BN + wn * (BN / 2) + j * 16 + lr) * 32 + csw];
    }
#pragma unroll
    for (int h = 0; h < 2; ++h)
#pragma unroll
      for (int i = 0; i < 4; ++i)
#pragma unroll
        for (int j = 0; j < FN; ++j)
          acc[i][j] = __builtin_amdgcn_mfma_f32_16x16x32_bf16(af[h][i], bfr[h][j], acc[i][j], 0, 0, 0);
    __syncthreads();
  }

  const int wrow0 = m0 + wm * 64;
  const int col0  = n0 + wn * (BN / 2);

  if constexpr (MODE == 0) {  // ---- QKV: bias + (q*0.125) + RoPE + scatter ----
    float v[4][FN][4];
#pragma unroll
    for (int i = 0; i < 4; ++i)
#pragma unroll
      for (int j = 0; j < FN; ++j)
#pragma unroll
        for (int r = 0; r < 4; ++r)
          v[i][j][r] = acc[i][j][r] + bias[wrow0 + i * 16 + kg * 4 + r];
    const int sec = wrow0 >> 9;            // 0=q 1=k 2=v
    const int hh  = (wrow0 & 511) >> 6;    // head
    if (sec < 2) {
      if (sec == 0) {                      // fold 1/sqrt(64) into q (pre-rope ok)
#pragma unroll
        for (int i = 0; i < 4; ++i)
#pragma unroll
          for (int j = 0; j < FN; ++j)
#pragma unroll
            for (int r = 0; r < 4; ++r) v[i][j][r] *= 0.125f;
      }
#pragma unroll
      for (int j = 0; j < FN; ++j) {
        const int t = (col0 + j * 16 + lr) & 1023;
#pragma unroll
        for (int r = 0; r < 4; ++r) {
          const int a = kg * 4 + r;
          const float cv = ctab[t * 16 + a], sv = stab[t * 16 + a];
          const float a0 = v[0][j][r], a1 = v[1][j][r];
          v[0][j][r] = a0 * cv - a1 * sv;
          v[1][j][r] = a1 * cv + a0 * sv;
        }
      }
      u16* dst = (sec == 0) ? o0 : o1;     // q,k: (B,H,T,64)
#pragma unroll
      for (int i = 0; i < 4; ++i)
#pragma unroll
        for (int j = 0; j < FN; ++j) {
          const int bt = col0 + j * 16 + lr;
          const int b = bt >> 10, t = bt & 1023;
          ushort4v pk;
#pragma unroll
          for (int r = 0; r < 4; ++r) pk[r] = f2bf(v[i][j][r]);
          *(ushort4v*)&dst[(((size_t)b * 8 + hh) * 1024 + t) * 64 + i * 16 + kg * 4] = pk;
        }
    } else {                               // v: (B,H,64,T)
#pragma unroll
      for (int i = 0; i < 4; ++i)
#pragma unroll
        for (int j = 0; j < FN; ++j) {
          const int bt = col0 + j * 16 + lr;
          const int b = bt >> 10, t = bt & 1023;
#pragma unroll
          for (int r = 0; r < 4; ++r) {
            const int dk = i * 16 + kg * 4 + r;
            o2[(((size_t)b * 8 + hh) * 64 + dk) * 1024 + t] = f2bf(v[i][j][r]);
          }
        }
    }
  } else if constexpr (MODE == 3) {  // ---- O-proj: +bias -> y1T (B,T,C) ----
#pragma unroll
    for (int i = 0; i < 4; ++i)
#pragma unroll
      for (int j = 0; j < FN; ++j) {
        const int bt = col0 + j * 16 + lr;
        const int c0 = wrow0 + i * 16 + kg * 4;
        ushort4v pk;
#pragma unroll
        for (int r = 0; r < 4; ++r) pk[r] = f2bf(acc[i][j][r] + bias[c0 + r]);
        *(ushort4v*)&o0[(size_t)bt * 512 + c0] = pk;
      }
  } else if constexpr (MODE == 4) {  // ---- conv1: relu(acc+b1)*mask -> h1pad ----
#pragma unroll
    for (int i = 0; i < 4; ++i) {
      const int r0 = wrow0 + i * 16 + kg * 4;
#pragma unroll
      for (int j = 0; j < FN; ++j) {
        const int bt = col0 + j * 16 + lr;
        const int b = bt >> 10, t = bt & 1023;
        const float mv = msk[(size_t)b * 1024 + t];
        ushort4v pk;
#pragma unroll
        for (int r = 0; r < 4; ++r)
          pk[r] = f2bf(fmaxf(acc[i][j][r] + bias[r0 + r], 0.f) * mv);
        *(ushort4v*)&o0[((size_t)(b * 1026 + t + 1)) * 2048 + r0] = pk;
      }
    }
  } else {                           // ---- conv2 split-K partial z -> o0 + z*S ----
    u16* dst = o0 + (size_t)blockIdx.z * 8 * 1024 * 512;
    const bool z0 = (blockIdx.z == 0);
#pragma unroll
    for (int i = 0; i < 4; ++i)
#pragma unroll
      for (int j = 0; j < FN; ++j) {
        const int bt = col0 + j * 16 + lr;
        const int b = bt >> 10, t = bt & 1023;
        const int c0 = wrow0 + i * 16 + kg * 4;
        const float mv = msk[(size_t)b * 1024 + t];
        ushort4v pk;
#pragma unroll
        for (int r = 0; r < 4; ++r) {
          const float bv = z0 ? bias[c0 + r] : 0.f;
          pk[r] = f2bf((acc[i][j][r] + bv) * mv);
        }
        *(ushort4v*)&dst[(size_t)bt * 512 + c0] = pk;
      }
  }
}

// ---------------------------------------------------------------------------
// Fused prep mega-kernel (unchanged).
// ---------------------------------------------------------------------------
__global__ __launch_bounds__(256) void k_prep(
    const float* __restrict__ wq, const float* __restrict__ wk,
    const float* __restrict__ wv, const float* __restrict__ wo,
    const float* __restrict__ w1, const float* __restrict__ w2,
    const float* __restrict__ bq, const float* __restrict__ bk,
    const float* __restrict__ bv, const float* __restrict__ am,
    u16* __restrict__ wqkv, u16* __restrict__ wob,
    u16* __restrict__ w1p, u16* __restrict__ w2p,
    float* __restrict__ bqkv, float* __restrict__ ctab, float* __restrict__ stab,
    unsigned* __restrict__ mbits, u16* __restrict__ x2p, u16* __restrict__ h1p)
{
  const int bid = blockIdx.x;
  if (bid < 4096) {
    const int seg = bid >> 10;
    const int i = (bid & 1023) * 256 + threadIdx.x;
    const float* src = (seg == 0) ? wq : (seg == 1) ? wk : (seg == 2) ? wv : wo;
    u16* dst = (seg < 3) ? (wqkv + (size_t)seg * 512 * 512) : wob;
    dst[i] = f2bf(src[i]);
  } else if (bid < 16384) {
    const int i = (bid - 4096) * 256 + threadIdx.x;
    const int f = i / 1536, rem = i % 1536;
    const int kk = rem >> 9, c = rem & 511;
    w1p[i] = f2bf(w1[f * 1536 + c * 3 + kk]);
  } else if (bid < 28672) {
    const int i = (bid - 16384) * 256 + threadIdx.x;
    const int c = i / 6144, rem = i % 6144;
    const int kk = rem >> 11, f = rem & 2047;
    w2p[i] = f2bf(w2[c * 6144 + f * 3 + kk]);
  } else if (bid < 29696) {
    const int i = (bid - 28672) * 256 + threadIdx.x;
    const float* src = am + (size_t)i * 32;
    unsigned w = 0;
#pragma unroll
    for (int q = 0; q < 32; ++q) w |= (src[q] != 0.f) ? (1u << q) : 0u;
    mbits[i] = w;
  } else if (bid < 29760) {
    const int i = (bid - 29696) * 256 + threadIdx.x;
    const int t = i >> 4, a = i & 15;
    const float theta = powf(10000.f, -(float)a / 16.f);
    const float ang = (float)t * theta;
    ctab[i] = cosf(ang);
    stab[i] = sinf(ang);
  } else if (bid == 29760) {
    for (int i = threadIdx.x; i < 1536; i += 256)
      bqkv[i] = (i < 512) ? bq[i] : (i < 1024) ? bk[i - 512] : bv[i - 1024];
  } else {
    int zb = bid - 29761;
    if (zb < 16) {
      const int b = zb >> 1;
      const size_t row = (zb & 1) ? 1025 : 0;
      u16* r = x2p + ((size_t)b * 1026 + row) * 512;
      for (int i = threadIdx.x; i < 512; i += 256) r[i] = 0;
    } else {
      zb -= 16;
      const int b = zb >> 1;
      const size_t row = (zb & 1) ? 1025 : 0;
      u16* r = h1p + ((size_t)b * 1026 + row) * 2048;
      for (int i = threadIdx.x; i < 2048; i += 256) r[i] = 0;
    }
  }
}

// tiled fp32 (B,R,TT) -> bf16 (B,TT,R) transpose-convert, column mask applied
__global__ __launch_bounds__(256) void k_tcvt(const float* __restrict__ in, u16* __restrict__ out,
                                              const float* __restrict__ msk, int R, int TT) {
  __shared__ u16 tile[64][65];
  const int b = blockIdx.z;
  const int r0 = blockIdx.x * 64, t0 = blockIdx.y * 64;
  const int tx = threadIdx.x & 63, ty = threadIdx.x >> 6;
  const float mv = msk ? msk[(size_t)b * TT + t0 + tx] : 1.f;
  const float* ib = in + (size_t)b * R * TT;
#pragma unroll
  for (int rr = ty; rr < 64; rr += 4)
    tile[rr][tx] = f2bf(ib[(size_t)(r0 + rr) * TT + t0 + tx] * mv);
  __syncthreads();
  u16* ob = out + (size_t)b * TT * R;
#pragma unroll
  for (int tt = ty; tt < 64; tt += 4)
    ob[(size_t)(t0 + tt) * R + r0 + tx] = tile[tx][tt];
}

// LN1: one wave per (b,t) row of 512. r = xbT + y1T (both (B,T,C) bf16).
__global__ __launch_bounds__(256) void k_ln1(
    const u16* __restrict__ xbT, const u16* __restrict__ y1T,
    const float* __restrict__ xm, const float* __restrict__ g,
    const float* __restrict__ be, u16* __restrict__ x2T, u16* __restrict__ x2p)
{
  const int lane = threadIdx.x & 63, wv = threadIdx.x >> 6;
  const int row = blockIdx.x * 4 + wv;          // b*1024 + t
  const int b = row >> 10, t = row & 1023;
  const size_t base = (size_t)row * 512 + lane * 8;
  ushort8v ux = *(const ushort8v*)&xbT[base];
  ushort8v uy = *(const ushort8v*)&y1T[base];
  float v[8];
  float sum = 0.f, ss = 0.f;
#pragma unroll
  for (int q = 0; q < 8; ++q) {
    v[q] = bf2f(ux[q]) + bf2f(uy[q]);
    sum += v[q]; ss += v[q] * v[q];
  }
#pragma unroll
  for (int o = 32; o; o >>= 1) { sum += __shfl_xor(sum, o); ss += __shfl_xor(ss, o); }
  const float mean = sum * (1.f / 512.f);
  const float var  = ss * (1.f / 512.f) - mean * mean;
  const float rs   = rsqrtf(var + 1e-4f);
  const float m    = xm[(size_t)b * 1024 + t];
  ushort8v on, om;
#pragma unroll
  for (int q = 0; q < 8; ++q) {
    const int c = lane * 8 + q;
    const float nv = (v[q] - mean) * rs * g[c] + be[c];
    on[q] = f2bf(nv);
    om[q] = f2bf(nv * m);
  }
  *(ushort8v*)&x2T[base] = on;
  *(ushort8v*)&x2p[((size_t)(b * 1026 + t + 1)) * 512 + lane * 8] = om;
}

// LN2 stats: one wave per row; r = x2T + 2 conv2 partials
__global__ __launch_bounds__(256) void k_ln2_stats(
    const u16* __restrict__ x2T, const u16* __restrict__ c2p,
    float2* __restrict__ mr)
{
  constexpr size_t S = (size_t)8 * 1024 * 512;
  const int lane = threadIdx.x & 63, wv = threadIdx.x >> 6;
  const int row = blockIdx.x * 4 + wv;
  const size_t base = (size_t)row * 512 + lane * 8;
  ushort8v u0 = *(const ushort8v*)&x2T[base];
  ushort8v u1 = *(const ushort8v*)&c2p[base];
  ushort8v u2 = *(const ushort8v*)&c2p[S + base];
  float sum = 0.f, ss = 0.f;
#pragma unroll
  for (int q = 0; q < 8; ++q) {
    const float v = bf2f(u0[q]) + bf2f(u1[q]) + bf2f(u2[q]);
    sum += v; ss += v * v;
  }
#pragma unroll
  for (int o = 32; o; o >>= 1) { sum += __shfl_xor(sum, o); ss += __shfl_xor(ss, o); }
  if (lane == 0) {
    const float mean = sum * (1.f / 512.f);
    const float var  = ss * (1.f / 512.f) - mean * mean;
    mr[row] = (float2){mean, rsqrtf(var + 1e-4f)};
  }
}

// LN2 write: normalize + transpose to out (B,C,T) fp32.
__global__ __launch_bounds__(256) void k_ln2_write(
    const u16* __restrict__ x2T, const u16* __restrict__ c2p,
    const float2* __restrict__ mr,
    const float* __restrict__ g, const float* __restrict__ be,
    float* __restrict__ out)
{
  constexpr size_t S = (size_t)8 * 1024 * 512;
  __shared__ float tile[64][65];
  const int cc0 = blockIdx.x * 64, t0 = blockIdx.y * 64, b = blockIdx.z;
  const int tid = threadIdx.x;
  const int c4 = (tid & 15) * 4;
  const int tr = tid >> 4;
  float g4[4], b4[4];
#pragma unroll
  for (int q = 0; q < 4; ++q) { g4[q] = g[cc0 + c4 + q]; b4[q] = be[cc0 + c4 + q]; }
#pragma unroll
  for (int it = 0; it < 4; ++it) {
    const int tt = tr + it * 16;
    const int row = b * 1024 + t0 + tt;
    const size_t base = (size_t)row * 512 + cc0 + c4;
    ushort4v u0 = *(const ushort4v*)&x2T[base];
    ushort4v u1 = *(const ushort4v*)&c2p[base];
    ushort4v u2 = *(const ushort4v*)&c2p[S + base];
    const float2 s = mr[row];
#pragma unroll
    for (int q = 0; q < 4; ++q) {
      const float v = bf2f(u0[q]) + bf2f(u1[q]) + bf2f(u2[q]);
      tile[tt][c4 + q] = (v - s.x) * s.y * g4[q] + b4[q];
    }
  }
  __syncthreads();
  const int tx = tid & 63, cg = tid >> 6;
#pragma unroll
  for (int c = cg; c < 64; c += 4)
    out[((size_t)b * 512 + cc0 + c) * 1024 + t0 + tx] = tile[tx][c];
}

// ---------------------------------------------------------------------------
extern "C" void kernel_launch(void* const* d_in, const int* in_sizes, int n_in,
                              void* d_out, int out_size, void* d_ws, size_t ws_size,
                              hipStream_t stream) {
  (void)in_sizes; (void)n_in; (void)out_size; (void)ws_size;
  const float* x   = (const float*)d_in[0];
  const float* xm  = (const float*)d_in[1];
  const float* am  = (const float*)d_in[2];
  const float* wq  = (const float*)d_in[3];
  const float* bq  = (const float*)d_in[4];
  const float* wk  = (const float*)d_in[5];
  const float* bk  = (const float*)d_in[6];
  const float* wv  = (const float*)d_in[7];
  const float* bv  = (const float*)d_in[8];
  const float* wo  = (const float*)d_in[9];
  const float* bo  = (const float*)d_in[10];
  const float* w1  = (const float*)d_in[11];
  const float* b1  = (const float*)d_in[12];
  const float* w2  = (const float*)d_in[13];
  const float* b2  = (const float*)d_in[14];
  const float* g1  = (const float*)d_in[15];
  const float* be1 = (const float*)d_in[16];
  const float* g2  = (const float*)d_in[17];
  const float* be2 = (const float*)d_in[18];
  float* out = (float*)d_out;

  char* ws = (char*)d_ws;
  size_t off = 0;
  auto alloc = [&](size_t bytes) { char* p = ws + off; off += (bytes + 255) & ~(size_t)255; return p; };

  u16*   wqkv = (u16*)  alloc((size_t)1536 * 512 * 2);
  u16*   wob  = (u16*)  alloc((size_t)512 * 512 * 2);
  u16*   w1p  = (u16*)  alloc((size_t)2048 * 1536 * 2);
  u16*   w2p  = (u16*)  alloc((size_t)512 * 6144 * 2);
  float* bqkv = (float*)alloc(1536 * 4);
  float* ctab = (float*)alloc(1024 * 16 * 4);
  float* stab = (float*)alloc(1024 * 16 * 4);
  unsigned* mbits = (unsigned*)alloc((size_t)8 * 1024 * 32 * 4);
  float2* mr  = (float2*)alloc((size_t)8192 * 8);
  u16*   x2T  = (u16*)  alloc((size_t)8 * 1024 * 512 * 2);   // LN1 out (B,T,C)
  u16*   x2p  = (u16*)  alloc((size_t)8 * 1026 * 512 * 2);   // LN1 out masked, padded
  u16*   h1p  = (u16*)  alloc((size_t)8 * 1026 * 2048 * 2);  // conv1 out, padded (B,1026,F)
  u16*   y1T  = (u16*)  alloc((size_t)8 * 1024 * 512 * 2);   // attn out (B,T,C)
  u16*   xbT  = (u16*)  alloc((size_t)8 * 1024 * 512 * 2);   // masked x^T (B,T,C)
  u16*   oT   = (u16*)  alloc((size_t)8 * 1024 * 512 * 2);   // attn O (B,T,C)
  u16*   qkv3 = (u16*)  alloc((size_t)3 * 8 * 8 * 1024 * 64 * 2); // q,k,v
  u16*   c2p  = (u16*)  alloc((size_t)2 * 8 * 1024 * 512 * 2);    // conv2 partials (2,B,T,C)

  u16* qb = qkv3;
  u16* kb = qkv3 + (size_t)8 * 8 * 1024 * 64;
  u16* vb = kb   + (size_t)8 * 8 * 1024 * 64;

  dim3 blk(256);

  // fused prep (weights, bias, rope, mask bits, pad rows) — one dispatch
  k_prep<<<dim3(29793), blk, 0, stream>>>(
      wq, wk, wv, wo, w1, w2, bq, bk, bv, am,
      wqkv, wob, w1p, w2p, bqkv, ctab, stab, mbits, x2p, h1p);

  // x^T (masked, bf16)
  k_tcvt<<<dim3(8, 16, 8), blk, 0, stream>>>(x, xbT, xm, 512, 1024);

  // QKV projection + bias + rope (q scaled 0.125) + head scatter
  k_cgemm<0, 128, 0><<<dim3(12, 64), blk, 0, stream>>>(
      wqkv, 512, xbT, 512, 512, qb, kb, vb, bqkv, ctab, stab, nullptr);

  // fused flash attention -> oT (B,T,C)
  k_fattn<<<dim3(8, 64), blk, 0, stream>>>(qb, kb, vb, mbits, oT);

  // y1 = wo o + bo -> y1T (B,T,C)
  k_cgemm<3, 64, 0><<<dim3(4, 128), blk, 0, stream>>>(
      wob, 512, oT, 512, 512, y1T, nullptr, nullptr, bo, nullptr, nullptr, nullptr);

  // LN1 rows -> x2T (residual) + x2p (masked, padded conv input)
  k_ln1<<<dim3(2048), blk, 0, stream>>>(xbT, y1T, xm, g1, be1, x2T, x2p);

  // conv path (contiguous im2col rows in padded layout)
  k_cgemm<4, 128, 512><<<dim3(16, 64), blk, 0, stream>>>(
      w1p, 1536, x2p, 0, 1536, h1p, nullptr, nullptr, b1, nullptr, nullptr, xm);
  // conv2: BN=64, split-K x2 (K-slice 3072 each) -> 2 contiguous partials c2p
  k_cgemm<5, 64, 2048><<<dim3(4, 128, 2), blk, 0, stream>>>(
      w2p, 6144, h1p, 0, 3072, c2p, nullptr, nullptr, b2, nullptr, nullptr, xm);

  // LN2: stats then transpose-normalize -> out (B,C,T) fp32
  k_ln2_stats<<<dim3(2048), blk, 0, stream>>>(x2T, c2p, mr);
  k_ln2_write<<<dim3(8, 16, 8), blk, 0, stream>>>(x2T, c2p, mr, g2, be2, out);
}

// Round 14
// 290.717 us; speedup vs baseline: 1.1374x; 1.0307x over previous
//
#include <hip/hip_runtime.h>

typedef unsigned short u16;
typedef __attribute__((ext_vector_type(4))) float floatx4;
typedef __attribute__((ext_vector_type(8))) __bf16 bf16x8;
typedef __attribute__((ext_vector_type(4))) unsigned short ushort4v;
typedef __attribute__((ext_vector_type(8))) unsigned short ushort8v;

#define DI __device__ __forceinline__

// ---- problem constants ----
// B=8, C=512, T=1024, H=8, F=2048, KS=3, head dim 64, ROPE_D=32, EPS=1e-4

DI u16 f2bf(float f) {
  union { float f; unsigned u; } v; v.f = f;
  unsigned r = v.u + 0x7fffu + ((v.u >> 16) & 1u);
  return (u16)(r >> 16);
}
DI float bf2f(u16 h) {
  union { unsigned u; float f; } v; v.u = ((unsigned)h) << 16;
  return v.f;
}

#define GLDS(g, l) __builtin_amdgcn_global_load_lds( \
    (const __attribute__((address_space(1))) unsigned int*)(g), \
    (__attribute__((address_space(3))) unsigned int*)(l), 16, 0, 0)

// ---------------------------------------------------------------------------
// Flash attention (R13 structure). R14: mask words prefetched one step ahead.
// ---------------------------------------------------------------------------
__global__ __launch_bounds__(256, 2) void k_fattn(
    const u16* __restrict__ qb, const u16* __restrict__ kb,
    const u16* __restrict__ vb, const unsigned* __restrict__ mb,
    u16* __restrict__ oT)
{
  __shared__ __align__(16) u16 Ps[4][32 * 64];
  const int tid  = threadIdx.x;
  const int wave = tid >> 6, lane = tid & 63;
  const int lr = lane & 15, kg = lane >> 4;
  const int qt = blockIdx.x, bh = blockIdx.y;
  const int bb = bh >> 3, hh = bh & 7;
  const int wq0 = qt * 128 + wave * 32;
  const float L2E = 1.44269504f;

  const u16* Qp = qb + (size_t)bh * 65536;
  const u16* Kp = kb + (size_t)bh * 65536;
  const u16* Vp = vb + (size_t)bh * 65536;
  u16* Pw = &Ps[wave][0];

  bf16x8 qf[2][2];
#pragma unroll
  for (int i = 0; i < 2; ++i)
#pragma unroll
    for (int h = 0; h < 2; ++h)
      qf[i][h] = *(const bf16x8*)&Qp[(wq0 + i * 16 + lr) * 64 + h * 32 + kg * 8];

  float l_b[2] = {0.f, 0.f};
  floatx4 o_acc[2][4];
#pragma unroll
  for (int i = 0; i < 2; ++i)
#pragma unroll
    for (int j = 0; j < 4; ++j) o_acc[i][j] = (floatx4){0.f, 0.f, 0.f, 0.f};

  bf16x8 kf[4][2], vf[4][2];
#pragma unroll
  for (int a = 0; a < 4; ++a)
#pragma unroll
    for (int h = 0; h < 2; ++h)
      kf[a][h] = *(const bf16x8*)&Kp[(a * 16 + lr) * 64 + h * 32 + kg * 8];

  // mask words for step 0, prefetched
  unsigned mw[2][2];
#pragma unroll
  for (int b = 0; b < 2; ++b) {
    const size_t rw = ((size_t)bb << 15) + ((size_t)(wq0 + b * 16 + lr) << 5);
    mw[b][0] = mb[rw]; mw[b][1] = mb[rw + 1];
  }

  for (int it = 0; it < 16; ++it) {
    const int s0 = it * 64;
    floatx4 sT[4][2];
    __builtin_amdgcn_s_setprio(1);
#pragma unroll
    for (int a = 0; a < 4; ++a) {
      sT[a][0] = (floatx4){0.f, 0.f, 0.f, 0.f};
      sT[a][1] = (floatx4){0.f, 0.f, 0.f, 0.f};
#pragma unroll
      for (int b = 0; b < 2; ++b)
#pragma unroll
        for (int h = 0; h < 2; ++h)
          sT[a][b] = __builtin_amdgcn_mfma_f32_16x16x32_bf16(kf[a][h], qf[b][h], sT[a][b], 0, 0, 0);
    }
    __builtin_amdgcn_s_setprio(0);
#pragma unroll
    for (int a = 0; a < 4; ++a)
#pragma unroll
      for (int h = 0; h < 2; ++h)
        vf[a][h] = *(const bf16x8*)&Vp[(a * 16 + lr) * 1024 + s0 + h * 32 + kg * 8];
    unsigned mwn[2][2];
    if (it < 15) {
      const int sn = s0 + 64;
#pragma unroll
      for (int a = 0; a < 4; ++a)
#pragma unroll
        for (int h = 0; h < 2; ++h)
          kf[a][h] = *(const bf16x8*)&Kp[(sn + a * 16 + lr) * 64 + h * 32 + kg * 8];
#pragma unroll
      for (int b = 0; b < 2; ++b) {
        const size_t rw = ((size_t)bb << 15) + ((size_t)(wq0 + b * 16 + lr) << 5) + (sn >> 5);
        mwn[b][0] = mb[rw]; mwn[b][1] = mb[rw + 1];
      }
    }
#pragma unroll
    for (int b = 0; b < 2; ++b) {
      float sum = 0.f;
#pragma unroll
      for (int a = 0; a < 4; ++a)
#pragma unroll
        for (int r = 0; r < 4; ++r) {
          const int sl = a * 16 + kg * 4 + r;
          float sv = sT[a][b][r];                 // q pre-scaled by 0.125
          const unsigned wsel = (sl & 32) ? mw[b][1] : mw[b][0];
          if (!((wsel >> (sl & 31)) & 1u)) sv = -10000.f;
          const float p = exp2f(sv * L2E);
          sT[a][b][r] = p;
          sum += p;
        }
      l_b[b] += sum;                              // cross-lane reduce deferred
#pragma unroll
      for (int a = 0; a < 4; ++a) {
        ushort4v pk;
#pragma unroll
        for (int r = 0; r < 4; ++r) {
          __bf16 hv = (__bf16)sT[a][b][r];
          pk[r] = *(u16*)&hv;
        }
        const int sl0 = a * 16 + kg * 4;
        *(ushort4v*)&Pw[(b * 16 + lr) * 64 + (sl0 ^ ((lr & 7) << 3))] = pk;
      }
    }
    if (it < 15) {
#pragma unroll
      for (int b = 0; b < 2; ++b) { mw[b][0] = mwn[b][0]; mw[b][1] = mwn[b][1]; }
    }
    asm volatile("s_waitcnt lgkmcnt(0)" ::: "memory");
    __builtin_amdgcn_sched_barrier(0);
    bf16x8 pa[2][2];
#pragma unroll
    for (int i = 0; i < 2; ++i)
#pragma unroll
      for (int h = 0; h < 2; ++h)
        pa[i][h] = *(const bf16x8*)&Pw[(i * 16 + lr) * 64 + (((h * 4 + kg) ^ (lr & 7)) << 3)];
    __builtin_amdgcn_s_setprio(1);
#pragma unroll
    for (int jd = 0; jd < 4; ++jd)
#pragma unroll
      for (int i = 0; i < 2; ++i)
#pragma unroll
        for (int h = 0; h < 2; ++h)
          o_acc[i][jd] = __builtin_amdgcn_mfma_f32_16x16x32_bf16(pa[i][h], vf[jd][h], o_acc[i][jd], 0, 0, 0);
    __builtin_amdgcn_s_setprio(0);
  }
  // epilogue: finish l reduce, divide, store oT (B,T,C)
#pragma unroll
  for (int i = 0; i < 2; ++i) {
    l_b[i] += __shfl_xor(l_b[i], 16);
    l_b[i] += __shfl_xor(l_b[i], 32);
  }
  float linv[2][4];
#pragma unroll
  for (int i = 0; i < 2; ++i)
#pragma unroll
    for (int r = 0; r < 4; ++r) linv[i][r] = 1.f / __shfl(l_b[i], kg * 4 + r);
#pragma unroll
  for (int i = 0; i < 2; ++i)
#pragma unroll
    for (int jd = 0; jd < 4; ++jd)
#pragma unroll
      for (int r = 0; r < 4; ++r) {
        const int t = wq0 + i * 16 + kg * 4 + r;
        const int c = hh * 64 + jd * 16 + lr;
        oT[((size_t)bb * 1024 + t) * 512 + c] = f2bf(o_acc[i][jd][r] * linv[i][r]);
      }
}

// ---------------------------------------------------------------------------
// Flat GEMM (R12/R13 structure, unchanged — proven best of 6 variants).
// ---------------------------------------------------------------------------
template<int MODE, int BN, int TAPK>
__global__ __launch_bounds__(256) void k_cgemm(
    const u16* __restrict__ A, int lda,
    const u16* __restrict__ Bsrc, int ldb,
    int K,
    u16* __restrict__ o0, u16* __restrict__ o1, u16* __restrict__ o2,
    const float* __restrict__ bias,
    const float* __restrict__ ctab, const float* __restrict__ stab,
    const float* __restrict__ msk)
{
  constexpr int BM = 128;
  constexpr int FN = BN / 32;
  __shared__ __align__(16) u16 As[2 * BM * 32];
  __shared__ __align__(16) u16 Bs[2 * BN * 32];

  const int tid  = threadIdx.x;
  const int wave = tid >> 6, lane = tid & 63;
  const int wm = wave >> 1, wn = wave & 1;
  const int lr = lane & 15, kg = lane >> 4;

  const int nwg = gridDim.x * gridDim.y;
  const int h0  = blockIdx.y * gridDim.x + blockIdx.x;
  const int cpx = nwg >> 3;
  const int tl  = (h0 & 7) * cpx + (h0 >> 3);
  const int bx  = tl % gridDim.x;
  const int by  = tl / gridDim.x;

  const int m0 = bx * BM, n0 = by * BN;
  const int koff = blockIdx.z * K;

  const u16* aP[2][BM / 64];
  const u16* bP[2][BN / 64];
#pragma unroll
  for (int h = 0; h < 2; ++h) {
#pragma unroll
    for (int ch = 0; ch < BM / 64; ++ch) {
      const int idx = ch * 256 + tid;
      const int row = idx >> 2;
      const int kk = (((idx & 3) ^ ((row >> 1) & 3)) << 3);
      aP[h][ch] = A + (size_t)(m0 + row) * lda + koff + h * 32 + kk;
    }
#pragma unroll
    for (int ch = 0; ch < BN / 64; ++ch) {
      const int idx = ch * 256 + tid;
      const int row = idx >> 2;
      const int kk = (((idx & 3) ^ ((row >> 1) & 3)) << 3);
      const int bt = n0 + row;
      size_t rowbase;
      if constexpr (TAPK == 0) {
        rowbase = (size_t)bt * ldb;
      } else {
        const int b = bt >> 10, t = bt & 1023;
        rowbase = ((size_t)(b * 1026 + t)) * TAPK;
      }
      bP[h][ch] = Bsrc + rowbase + koff + h * 32 + kk;
    }
  }

  floatx4 acc[4][FN];
#pragma unroll
  for (int i = 0; i < 4; ++i)
#pragma unroll
    for (int j = 0; j < FN; ++j) acc[i][j] = (floatx4){0.f, 0.f, 0.f, 0.f};

  const int csw = (kg ^ ((lr >> 1) & 3)) * 8;

  for (int k0 = 0; k0 < K; k0 += 64) {
#pragma unroll
    for (int h = 0; h < 2; ++h) {
#pragma unroll
      for (int ch = 0; ch < BM / 64; ++ch)
        GLDS(aP[h][ch] + k0, &As[h * BM * 32 + (ch * 256 + tid) * 8]);
#pragma unroll
      for (int ch = 0; ch < BN / 64; ++ch)
        GLDS(bP[h][ch] + k0, &Bs[h * BN * 32 + (ch * 256 + tid) * 8]);
    }
    __syncthreads();
    bf16x8 af[2][4], bfr[2][FN];
#pragma unroll
    for (int h = 0; h < 2; ++h) {
#pragma unroll
      for (int i = 0; i < 4; ++i)
        af[h][i] = *(const bf16x8*)&As[(h * BM + wm * 64 + i * 16 + lr) * 32 + csw];
#pragma unroll
      for (int j = 0; j < FN; ++j)
        bfr[h][j] = *(const bf16x8*)&Bs[(h * BN + wn * (BN / 2) + j * 16 + lr) * 32 + csw];
    }
#pragma unroll
    for (int h = 0; h < 2; ++h)
#pragma unroll
      for (int i = 0; i < 4; ++i)
#pragma unroll
        for (int j = 0; j < FN; ++j)
          acc[i][j] = __builtin_amdgcn_mfma_f32_16x16x32_bf16(af[h][i], bfr[h][j], acc[i][j], 0, 0, 0);
    __syncthreads();
  }

  const int wrow0 = m0 + wm * 64;
  const int col0  = n0 + wn * (BN / 2);

  if constexpr (MODE == 0) {  // ---- QKV: bias + (q*0.125) + RoPE + scatter ----
    float v[4][FN][4];
#pragma unroll
    for (int i = 0; i < 4; ++i)
#pragma unroll
      for (int j = 0; j < FN; ++j)
#pragma unroll
        for (int r = 0; r < 4; ++r)
          v[i][j][r] = acc[i][j][r] + bias[wrow0 + i * 16 + kg * 4 + r];
    const int sec = wrow0 >> 9;
    const int hh  = (wrow0 & 511) >> 6;
    if (sec < 2) {
      if (sec == 0) {
#pragma unroll
        for (int i = 0; i < 4; ++i)
#pragma unroll
          for (int j = 0; j < FN; ++j)
#pragma unroll
            for (int r = 0; r < 4; ++r) v[i][j][r] *= 0.125f;
      }
#pragma unroll
      for (int j = 0; j < FN; ++j) {
        const int t = (col0 + j * 16 + lr) & 1023;
#pragma unroll
        for (int r = 0; r < 4; ++r) {
          const int a = kg * 4 + r;
          const float cv = ctab[t * 16 + a], sv = stab[t * 16 + a];
          const float a0 = v[0][j][r], a1 = v[1][j][r];
          v[0][j][r] = a0 * cv - a1 * sv;
          v[1][j][r] = a1 * cv + a0 * sv;
        }
      }
      u16* dst = (sec == 0) ? o0 : o1;
#pragma unroll
      for (int i = 0; i < 4; ++i)
#pragma unroll
        for (int j = 0; j < FN; ++j) {
          const int bt = col0 + j * 16 + lr;
          const int b = bt >> 10, t = bt & 1023;
          ushort4v pk;
#pragma unroll
          for (int r = 0; r < 4; ++r) pk[r] = f2bf(v[i][j][r]);
          *(ushort4v*)&dst[(((size_t)b * 8 + hh) * 1024 + t) * 64 + i * 16 + kg * 4] = pk;
        }
    } else {
#pragma unroll
      for (int i = 0; i < 4; ++i)
#pragma unroll
        for (int j = 0; j < FN; ++j) {
          const int bt = col0 + j * 16 + lr;
          const int b = bt >> 10, t = bt & 1023;
#pragma unroll
          for (int r = 0; r < 4; ++r) {
            const int dk = i * 16 + kg * 4 + r;
            o2[(((size_t)b * 8 + hh) * 64 + dk) * 1024 + t] = f2bf(v[i][j][r]);
          }
        }
    }
  } else if constexpr (MODE == 3) {
#pragma unroll
    for (int i = 0; i < 4; ++i)
#pragma unroll
      for (int j = 0; j < FN; ++j) {
        const int bt = col0 + j * 16 + lr;
        const int c0 = wrow0 + i * 16 + kg * 4;
        ushort4v pk;
#pragma unroll
        for (int r = 0; r < 4; ++r) pk[r] = f2bf(acc[i][j][r] + bias[c0 + r]);
        *(ushort4v*)&o0[(size_t)bt * 512 + c0] = pk;
      }
  } else if constexpr (MODE == 4) {
#pragma unroll
    for (int i = 0; i < 4; ++i) {
      const int r0 = wrow0 + i * 16 + kg * 4;
#pragma unroll
      for (int j = 0; j < FN; ++j) {
        const int bt = col0 + j * 16 + lr;
        const int b = bt >> 10, t = bt & 1023;
        const float mv = msk[(size_t)b * 1024 + t];
        ushort4v pk;
#pragma unroll
        for (int r = 0; r < 4; ++r)
          pk[r] = f2bf(fmaxf(acc[i][j][r] + bias[r0 + r], 0.f) * mv);
        *(ushort4v*)&o0[((size_t)(b * 1026 + t + 1)) * 2048 + r0] = pk;
      }
    }
  } else {
    u16* dst = o0 + (size_t)blockIdx.z * 8 * 1024 * 512;
    const bool z0 = (blockIdx.z == 0);
#pragma unroll
    for (int i = 0; i < 4; ++i)
#pragma unroll
      for (int j = 0; j < FN; ++j) {
        const int bt = col0 + j * 16 + lr;
        const int b = bt >> 10, t = bt & 1023;
        const int c0 = wrow0 + i * 16 + kg * 4;
        const float mv = msk[(size_t)b * 1024 + t];
        ushort4v pk;
#pragma unroll
        for (int r = 0; r < 4; ++r) {
          const float bv = z0 ? bias[c0 + r] : 0.f;
          pk[r] = f2bf((acc[i][j][r] + bv) * mv);
        }
        *(ushort4v*)&dst[(size_t)bt * 512 + c0] = pk;
      }
  }
}

// ---------------------------------------------------------------------------
// Fused prep mega-kernel. R14: coalesced w1/w2 repacks (read 3 consecutive
// floats per thread, write 3 coalesced kk-plane streams) + x^T transpose
// (old k_tcvt) folded in as trailing blocks.
// ---------------------------------------------------------------------------
__global__ __launch_bounds__(256) void k_prep(
    const float* __restrict__ wq, const float* __restrict__ wk,
    const float* __restrict__ wv, const float* __restrict__ wo,
    const float* __restrict__ w1, const float* __restrict__ w2,
    const float* __restrict__ bq, const float* __restrict__ bk,
    const float* __restrict__ bv, const float* __restrict__ am,
    const float* __restrict__ x, const float* __restrict__ xm,
    u16* __restrict__ wqkv, u16* __restrict__ wob,
    u16* __restrict__ w1p, u16* __restrict__ w2p,
    float* __restrict__ bqkv, float* __restrict__ ctab, float* __restrict__ stab,
    unsigned* __restrict__ mbits, u16* __restrict__ x2p, u16* __restrict__ h1p,
    u16* __restrict__ xbT)
{
  __shared__ u16 tile[64][65];
  const int bid = blockIdx.x;
  if (bid < 4096) {                      // wq/wk/wv -> wqkv, wo -> wob
    const int seg = bid >> 10;
    const int i = (bid & 1023) * 256 + threadIdx.x;
    const float* src = (seg == 0) ? wq : (seg == 1) ? wk : (seg == 2) ? wv : wo;
    u16* dst = (seg < 3) ? (wqkv + (size_t)seg * 512 * 512) : wob;
    dst[i] = f2bf(src[i]);
  } else if (bid < 8192) {               // repack w1 (F,C,KS)->(F,KS,C), coalesced
    const int i = (bid - 4096) * 256 + threadIdx.x;   // over 2048*512 (f,c) pairs
    const int f = i >> 9, c = i & 511;
    const float* s = &w1[(size_t)f * 1536 + c * 3];
#pragma unroll
    for (int kk = 0; kk < 3; ++kk)
      w1p[(size_t)f * 1536 + kk * 512 + c] = f2bf(s[kk]);
  } else if (bid < 12288) {              // repack w2 (C,F,KS)->(C,KS,F), coalesced
    const int i = (bid - 8192) * 256 + threadIdx.x;   // over 512*2048 (c,f) pairs
    const int c = i >> 11, f = i & 2047;
    const float* s = &w2[(size_t)c * 6144 + f * 3];
#pragma unroll
    for (int kk = 0; kk < 3; ++kk)
      w2p[(size_t)c * 6144 + kk * 2048 + f] = f2bf(s[kk]);
  } else if (bid < 13312) {              // mask bit-pack
    const int i = (bid - 12288) * 256 + threadIdx.x;
    const float* src = am + (size_t)i * 32;
    unsigned w = 0;
#pragma unroll
    for (int q = 0; q < 32; ++q) w |= (src[q] != 0.f) ? (1u << q) : 0u;
    mbits[i] = w;
  } else if (bid < 13376) {              // rope tables
    const int i = (bid - 13312) * 256 + threadIdx.x;
    const int t = i >> 4, a = i & 15;
    const float theta = powf(10000.f, -(float)a / 16.f);
    const float ang = (float)t * theta;
    ctab[i] = cosf(ang);
    stab[i] = sinf(ang);
  } else if (bid == 13376) {             // bias concat
    for (int i = threadIdx.x; i < 1536; i += 256)
      bqkv[i] = (i < 512) ? bq[i] : (i < 1024) ? bk[i - 512] : bv[i - 1024];
  } else if (bid < 13409) {              // zero pad rows of x2p / h1p
    int zb = bid - 13377;                // 0..31
    if (zb < 16) {
      const int b = zb >> 1;
      const size_t row = (zb & 1) ? 1025 : 0;
      u16* r = x2p + ((size_t)b * 1026 + row) * 512;
      for (int i = threadIdx.x; i < 512; i += 256) r[i] = 0;
    } else {
      zb -= 16;
      const int b = zb >> 1;
      const size_t row = (zb & 1) ? 1025 : 0;
      u16* r = h1p + ((size_t)b * 1026 + row) * 2048;
      for (int i = threadIdx.x; i < 2048; i += 256) r[i] = 0;
    }
  } else {                               // x^T transpose (was k_tcvt): 1024 blocks
    const int zb = bid - 13409;          // (r-tile 8) x (t-tile 16) x (b 8)
    const int b = zb & 7, tt0 = (zb >> 3) & 15, rr0 = zb >> 7;
    const int r0 = rr0 * 64, t0 = tt0 * 64;
    const int tx = threadIdx.x & 63, ty = threadIdx.x >> 6;
    const float mv = xm[(size_t)b * 1024 + t0 + tx];
    const float* ib = x + (size_t)b * 512 * 1024;
#pragma unroll
    for (int rr = ty; rr < 64; rr += 4)
      tile[rr][tx] = f2bf(ib[(size_t)(r0 + rr) * 1024 + t0 + tx] * mv);
    __syncthreads();
    u16* ob = xbT + (size_t)b * 1024 * 512;
#pragma unroll
    for (int t2 = ty; t2 < 64; t2 += 4)
      ob[(size_t)(t0 + t2) * 512 + r0 + tx] = tile[tx][t2];
  }
}

// LN1: one wave per (b,t) row of 512. r = xbT + y1T (both (B,T,C) bf16).
__global__ __launch_bounds__(256) void k_ln1(
    const u16* __restrict__ xbT, const u16* __restrict__ y1T,
    const float* __restrict__ xm, const float* __restrict__ g,
    const float* __restrict__ be, u16* __restrict__ x2T, u16* __restrict__ x2p)
{
  const int lane = threadIdx.x & 63, wv = threadIdx.x >> 6;
  const int row = blockIdx.x * 4 + wv;
  const int b = row >> 10, t = row & 1023;
  const size_t base = (size_t)row * 512 + lane * 8;
  ushort8v ux = *(const ushort8v*)&xbT[base];
  ushort8v uy = *(const ushort8v*)&y1T[base];
  float v[8];
  float sum = 0.f, ss = 0.f;
#pragma unroll
  for (int q = 0; q < 8; ++q) {
    v[q] = bf2f(ux[q]) + bf2f(uy[q]);
    sum += v[q]; ss += v[q] * v[q];
  }
#pragma unroll
  for (int o = 32; o; o >>= 1) { sum += __shfl_xor(sum, o); ss += __shfl_xor(ss, o); }
  const float mean = sum * (1.f / 512.f);
  const float var  = ss * (1.f / 512.f) - mean * mean;
  const float rs   = rsqrtf(var + 1e-4f);
  const float m    = xm[(size_t)b * 1024 + t];
  ushort8v on, om;
#pragma unroll
  for (int q = 0; q < 8; ++q) {
    const int c = lane * 8 + q;
    const float nv = (v[q] - mean) * rs * g[c] + be[c];
    on[q] = f2bf(nv);
    om[q] = f2bf(nv * m);
  }
  *(ushort8v*)&x2T[base] = on;
  *(ushort8v*)&x2p[((size_t)(b * 1026 + t + 1)) * 512 + lane * 8] = om;
}

// LN2 stats: one wave per row; r = x2T + 2 conv2 partials
__global__ __launch_bounds__(256) void k_ln2_stats(
    const u16* __restrict__ x2T, const u16* __restrict__ c2p,
    float2* __restrict__ mr)
{
  constexpr size_t S = (size_t)8 * 1024 * 512;
  const int lane = threadIdx.x & 63, wv = threadIdx.x >> 6;
  const int row = blockIdx.x * 4 + wv;
  const size_t base = (size_t)row * 512 + lane * 8;
  ushort8v u0 = *(const ushort8v*)&x2T[base];
  ushort8v u1 = *(const ushort8v*)&c2p[base];
  ushort8v u2 = *(const ushort8v*)&c2p[S + base];
  float sum = 0.f, ss = 0.f;
#pragma unroll
  for (int q = 0; q < 8; ++q) {
    const float v = bf2f(u0[q]) + bf2f(u1[q]) + bf2f(u2[q]);
    sum += v; ss += v * v;
  }
#pragma unroll
  for (int o = 32; o; o >>= 1) { sum += __shfl_xor(sum, o); ss += __shfl_xor(ss, o); }
  if (lane == 0) {
    const float mean = sum * (1.f / 512.f);
    const float var  = ss * (1.f / 512.f) - mean * mean;
    mr[row] = (float2){mean, rsqrtf(var + 1e-4f)};
  }
}

// LN2 write: normalize + transpose to out (B,C,T) fp32.
__global__ __launch_bounds__(256) void k_ln2_write(
    const u16* __restrict__ x2T, const u16* __restrict__ c2p,
    const float2* __restrict__ mr,
    const float* __restrict__ g, const float* __restrict__ be,
    float* __restrict__ out)
{
  constexpr size_t S = (size_t)8 * 1024 * 512;
  __shared__ float tile[64][65];
  const int cc0 = blockIdx.x * 64, t0 = blockIdx.y * 64, b = blockIdx.z;
  const int tid = threadIdx.x;
  const int c4 = (tid & 15) * 4;
  const int tr = tid >> 4;
  float g4[4], b4[4];
#pragma unroll
  for (int q = 0; q < 4; ++q) { g4[q] = g[cc0 + c4 + q]; b4[q] = be[cc0 + c4 + q]; }
#pragma unroll
  for (int it = 0; it < 4; ++it) {
    const int tt = tr + it * 16;
    const int row = b * 1024 + t0 + tt;
    const size_t base = (size_t)row * 512 + cc0 + c4;
    ushort4v u0 = *(const ushort4v*)&x2T[base];
    ushort4v u1 = *(const ushort4v*)&c2p[base];
    ushort4v u2 = *(const ushort4v*)&c2p[S + base];
    const float2 s = mr[row];
#pragma unroll
    for (int q = 0; q < 4; ++q) {
      const float v = bf2f(u0[q]) + bf2f(u1[q]) + bf2f(u2[q]);
      tile[tt][c4 + q] = (v - s.x) * s.y * g4[q] + b4[q];
    }
  }
  __syncthreads();
  const int tx = tid & 63, cg = tid >> 6;
#pragma unroll
  for (int c = cg; c < 64; c += 4)
    out[((size_t)b * 512 + cc0 + c) * 1024 + t0 + tx] = tile[tx][c];
}

// ---------------------------------------------------------------------------
extern "C" void kernel_launch(void* const* d_in, const int* in_sizes, int n_in,
                              void* d_out, int out_size, void* d_ws, size_t ws_size,
                              hipStream_t stream) {
  (void)in_sizes; (void)n_in; (void)out_size; (void)ws_size;
  const float* x   = (const float*)d_in[0];
  const float* xm  = (const float*)d_in[1];
  const float* am  = (const float*)d_in[2];
  const float* wq  = (const float*)d_in[3];
  const float* bq  = (const float*)d_in[4];
  const float* wk  = (const float*)d_in[5];
  const float* bk  = (const float*)d_in[6];
  const float* wv  = (const float*)d_in[7];
  const float* bv  = (const float*)d_in[8];
  const float* wo  = (const float*)d_in[9];
  const float* bo  = (const float*)d_in[10];
  const float* w1  = (const float*)d_in[11];
  const float* b1  = (const float*)d_in[12];
  const float* w2  = (const float*)d_in[13];
  const float* b2  = (const float*)d_in[14];
  const float* g1  = (const float*)d_in[15];
  const float* be1 = (const float*)d_in[16];
  const float* g2  = (const float*)d_in[17];
  const float* be2 = (const float*)d_in[18];
  float* out = (float*)d_out;

  char* ws = (char*)d_ws;
  size_t off = 0;
  auto alloc = [&](size_t bytes) { char* p = ws + off; off += (bytes + 255) & ~(size_t)255; return p; };

  u16*   wqkv = (u16*)  alloc((size_t)1536 * 512 * 2);
  u16*   wob  = (u16*)  alloc((size_t)512 * 512 * 2);
  u16*   w1p  = (u16*)  alloc((size_t)2048 * 1536 * 2);
  u16*   w2p  = (u16*)  alloc((size_t)512 * 6144 * 2);
  float* bqkv = (float*)alloc(1536 * 4);
  float* ctab = (float*)alloc(1024 * 16 * 4);
  float* stab = (float*)alloc(1024 * 16 * 4);
  unsigned* mbits = (unsigned*)alloc((size_t)8 * 1024 * 32 * 4);
  float2* mr  = (float2*)alloc((size_t)8192 * 8);
  u16*   x2T  = (u16*)  alloc((size_t)8 * 1024 * 512 * 2);
  u16*   x2p  = (u16*)  alloc((size_t)8 * 1026 * 512 * 2);
  u16*   h1p  = (u16*)  alloc((size_t)8 * 1026 * 2048 * 2);
  u16*   y1T  = (u16*)  alloc((size_t)8 * 1024 * 512 * 2);
  u16*   xbT  = (u16*)  alloc((size_t)8 * 1024 * 512 * 2);
  u16*   oT   = (u16*)  alloc((size_t)8 * 1024 * 512 * 2);
  u16*   qkv3 = (u16*)  alloc((size_t)3 * 8 * 8 * 1024 * 64 * 2);
  u16*   c2p  = (u16*)  alloc((size_t)2 * 8 * 1024 * 512 * 2);

  u16* qb = qkv3;
  u16* kb = qkv3 + (size_t)8 * 8 * 1024 * 64;
  u16* vb = kb   + (size_t)8 * 8 * 1024 * 64;

  dim3 blk(256);

  // fused prep (weights, bias, rope, mask bits, pad rows, x^T) — one dispatch
  k_prep<<<dim3(14433), blk, 0, stream>>>(
      wq, wk, wv, wo, w1, w2, bq, bk, bv, am, x, xm,
      wqkv, wob, w1p, w2p, bqkv, ctab, stab, mbits, x2p, h1p, xbT);

  // QKV projection + bias + rope (q scaled 0.125) + head scatter
  k_cgemm<0, 128, 0><<<dim3(12, 64), blk, 0, stream>>>(
      wqkv, 512, xbT, 512, 512, qb, kb, vb, bqkv, ctab, stab, nullptr);

  // fused flash attention -> oT (B,T,C)
  k_fattn<<<dim3(8, 64), blk, 0, stream>>>(qb, kb, vb, mbits, oT);

  // y1 = wo o + bo -> y1T (B,T,C)
  k_cgemm<3, 64, 0><<<dim3(4, 128), blk, 0, stream>>>(
      wob, 512, oT, 512, 512, y1T, nullptr, nullptr, bo, nullptr, nullptr, nullptr);

  // LN1 rows -> x2T (residual) + x2p (masked, padded conv input)
  k_ln1<<<dim3(2048), blk, 0, stream>>>(xbT, y1T, xm, g1, be1, x2T, x2p);

  // conv path (contiguous im2col rows in padded layout)
  k_cgemm<4, 128, 512><<<dim3(16, 64), blk, 0, stream>>>(
      w1p, 1536, x2p, 0, 1536, h1p, nullptr, nullptr, b1, nullptr, nullptr, xm);
  // conv2: BN=64, split-K x2 -> 2 contiguous partials c2p
  k_cgemm<5, 64, 2048><<<dim3(4, 128, 2), blk, 0, stream>>>(
      w2p, 6144, h1p, 0, 3072, c2p, nullptr, nullptr, b2, nullptr, nullptr, xm);

  // LN2: stats then transpose-normalize -> out (B,C,T) fp32
  k_ln2_stats<<<dim3(2048), blk, 0, stream>>>(x2T, c2p, mr);
  k_ln2_write<<<dim3(8, 16, 8), blk, 0, stream>>>(x2T, c2p, mr, g2, be2, out);
}